// Round 4
// baseline (221.408 us; speedup 1.0000x reference)
//
#include <hip/hip_runtime.h>
#include <math.h>

// SpectralPooling: out = Re(ifft3_32(pad32(crop24(Re(fft3_48(x))))))  per (b,c) volume.
// bc = 256 volumes of 48^3 fp32 -> 256 x 32^3 fp32.
//
// r13: mono-kernel dataflow (r12: FETCH dropped to ~x-only = L2/L3 locality works)
// with the parallelism restored: 4 SUB-BLOCKS PER BC (grid 1024 = 4 blocks/CU,
// 12 waves/CU vs r12's 3). Phase boundaries are per-bc arrive-and-spin syncs on
// device-scope atomics (G16 pattern: release-add, relaxed spin, acquire load).
// Deadlock audit: 192thr/27648B-LDS/<=128 VGPR (launch_bounds(192,4)) -> >=4
// blocks/CU capacity -> all 1024 blocks co-resident -> spins always progress.
// Sub-blocks of one bc are blk%256==bc -> same XCD under round-robin (locality
// heuristic only; correctness is carried by the fences).
//  phase1 (12 slabs/sb): D1 = T1*X ; D2 = D1*T2t ; recombine -> V[bc]
//  phase2 (6 k3/sb):  [Wr;Wi](64x24) = M_comb(64x96) * [Vr;Vi](96x24) -> W[bc]
//  phase3 (8 m1/sb):  [Zr;Zi] = MB2*[Wr;Wi] ; out = Z*TB3
// Split-f16 everywhere: P = Ahi*Bhi + Ahi*Blo + Alo*Bhi (~22 mantissa bits).
// GEMM bodies / frag layouts / barrier schedules verbatim from r12 (verified).
//
// d_ws: float2 V[256][24][48][24] (56,623,104 B), float2 W[256][32][24][24]
//       (37,748,736 B), int cnt[2][256] at offset 94,371,840 (re-zeroed per launch).

#define TWO_PI_48 0.13089969389957470f
#define TWO_PI_32 0.19634954084936207f
#define NORM_F    1.6611664e-05f         // 1/(48^1.5 * 32^1.5)

typedef _Float16 half8  __attribute__((ext_vector_type(8)));
typedef _Float16 half4v __attribute__((ext_vector_type(4)));
typedef float    f32x4  __attribute__((ext_vector_type(4)));

// Frag-layout tables: [hi/lo][tile][kstep][lane][j]
// A-frag element = A[tile*16 + (l&15)][ks*32 + (l>>4)*8 + j]
// B-frag element = B[ks*32 + (l>>4)*8 + j][tile*16 + (l&15)]
__device__ _Float16 T1frag[2][3][2][64][8];
__device__ _Float16 T2frag[2][3][2][64][8];
__device__ __align__(16) _Float16 TK2frag[2][4][3][64][8];  // M_comb 64x96
__device__ __align__(16) _Float16 MB2frag[2][4][2][64][8];  // 64x48 (pad 64)
__device__ __align__(16) _Float16 TB3frag[2][2][2][64][8];  // 48(pad64)x32

__device__ int g_twdone = 0;   // lazy-init flag (module-lifetime, set post-init)

__global__ void k_init_tw(int* __restrict__ cnt) {
  const int idx = blockIdx.x * 256 + threadIdx.x;   // 0..15359
  if (idx < 512) cnt[idx] = 0;                      // re-zero sync counters EVERY launch
  if (g_twdone) return;                             // tables already built (pure consts)
  if (idx < 3072) {                                 // K1 tables (verified r5)
    const int j  = idx & 7;
    const int l  = (idx >> 3) & 63;
    const int ks = (idx >> 9) & 1;
    const int t  = idx >> 10;
    const int k  = ks * 32 + (l >> 4) * 8 + j;
    {
      const int m = t * 16 + (l & 15);
      float v = 0.f;
      if (k < 48) {
        const float a = (float)(((m % 24) * k) % 48) * TWO_PI_48;
        v = (m < 24) ? cosf(a) : -sinf(a);
      }
      const _Float16 h = (_Float16)v;
      T1frag[0][t][ks][l][j] = h;
      T1frag[1][t][ks][l][j] = (_Float16)(v - (float)h);
    }
    {
      const int c = t * 16 + (l & 15);
      float v = 0.f;
      if (k < 48) {
        const float a = (float)(((c % 24) * k) % 48) * TWO_PI_48;
        v = (c < 24) ? cosf(a) : sinf(a);
      }
      const _Float16 h = (_Float16)v;
      T2frag[0][t][ks][l][j] = h;
      T2frag[1][t][ks][l][j] = (_Float16)(v - (float)h);
    }
  } else if (idx < 3072 + 6144) {                   // K2: M_comb (A3+B1 fused)
    const int local = idx - 3072;
    const int j = local & 7, l = (local >> 3) & 63;
    const int rest = local >> 9;                    // 0..11
    const int ks = rest % 3, mt = rest / 3;
    const int m   = mt * 16 + (l & 15);             // 0..63
    const int kap = ks * 32 + (l >> 4) * 8 + j;     // 0..95
    const int n1  = kap % 48;
    const bool isVi = kap >= 48;
    const int m1  = m & 31;
    const bool isWi = m >= 32;
    float acc = 0.f;
    for (int k1 = 0; k1 < 24; ++k1) {
      float s32v, c32v, s48v, c48v;
      sincosf((float)((k1 * m1) % 32) * TWO_PI_32, &s32v, &c32v);
      sincosf((float)((k1 * n1) % 48) * TWO_PI_48, &s48v, &c48v);
      acc = fmaf(isWi ? s32v : c32v, isVi ? s48v : c48v, acc);
    }
    const _Float16 h = (_Float16)acc;
    TK2frag[0][mt][ks][l][j] = h;
    TK2frag[1][mt][ks][l][j] = (_Float16)(acc - (float)h);
  } else if (idx < 3072 + 6144 + 4096) {            // K3: MB2 (B2 A-matrix)
    const int local = idx - (3072 + 6144);
    const int j = local & 7, l = (local >> 3) & 63;
    const int rest = local >> 9;                    // 0..7
    const int ks = rest & 1, mt = rest >> 1;
    const int m   = mt * 16 + (l & 15);             // 0..63
    const int kap = ks * 32 + (l >> 4) * 8 + j;     // 0..63
    float v = 0.f;
    if (kap < 48) {
      const int k2 = kap % 24;
      const int m2 = m & 31;
      float s, c;
      sincosf((float)((k2 * m2) % 32) * TWO_PI_32, &s, &c);
      if (m < 32) v = (kap < 24) ? c : -s;   // Zr = sum Wr*c - Wi*s
      else        v = (kap < 24) ? s :  c;   // Zi = sum Wr*s + Wi*c
    }
    const _Float16 h = (_Float16)v;
    MB2frag[0][mt][ks][l][j] = h;
    MB2frag[1][mt][ks][l][j] = (_Float16)(v - (float)h);
  } else if (idx < 15360) {                         // K3: TB3 (B3 B-matrix)
    const int local = idx - (3072 + 6144 + 4096);
    const int j = local & 7, l = (local >> 3) & 63;
    const int rest = local >> 9;                    // 0..3
    const int ks = rest & 1, nt = rest >> 1;
    const int m3  = nt * 16 + (l & 15);             // col 0..31
    const int kap = ks * 32 + (l >> 4) * 8 + j;     // 0..63
    float v = 0.f;
    if (kap < 48) {
      const int k3 = kap % 24;
      float s, c;
      sincosf((float)((k3 * m3) % 32) * TWO_PI_32, &s, &c);
      v = (kap < 24) ? c : -s;               // out = sum Zr*c - Zi*s
    }
    const _Float16 h = (_Float16)v;
    TB3frag[0][nt][ks][l][j] = h;
    TB3frag[1][nt][ks][l][j] = (_Float16)(v - (float)h);
  }
}

__device__ inline void split8(const float* qf, half8& h, half8& lo) {
#pragma unroll
  for (int j = 0; j < 8; ++j) {
    const _Float16 hh = (_Float16)qf[j];
    h[j]  = hh;
    lo[j] = (_Float16)(qf[j] - (float)hh);
  }
}

// Per-bc 4-way arrive-and-spin sync. Release-add publishes this block's prior
// global writes (pre-barrier waitcnt drained them to L2; release does the L2
// writeback). Relaxed spin (no repeated cache-inv); single acquire load after
// exit invalidates stale lines before partner data is read.
__device__ inline void sync_bc4(int* ctr) {
  __syncthreads();
  if (threadIdx.x == 0) {
    __hip_atomic_fetch_add(ctr, 1, __ATOMIC_RELEASE, __HIP_MEMORY_SCOPE_AGENT);
    while (__hip_atomic_load(ctr, __ATOMIC_RELAXED, __HIP_MEMORY_SCOPE_AGENT) < 4)
      __builtin_amdgcn_s_sleep(2);
    (void)__hip_atomic_load(ctr, __ATOMIC_ACQUIRE, __HIP_MEMORY_SCOPE_AGENT);
  }
  __syncthreads();
}

// ---------------- mono kernel: 4 sub-blocks per bc, 192 threads ----------------
// LDS pool aliasing (sequential phases, barrier-fenced):
//   phase1: arenaA = pool[0:13824], arenaB = pool[13824:27648]  (ping-pong X/D2 vs U)
//   phase2: Bb = (float*)pool, 48*100*4 = 19200 B
//   phase3: Bt = (float*)pool (8704 B), Zb = (float*)(pool+8704) (8704 B)
__global__ __launch_bounds__(192, 4) void k_mono(const float* __restrict__ x,
                                                 float2* __restrict__ V,
                                                 float2* __restrict__ W,
                                                 float* __restrict__ out,
                                                 int* __restrict__ cnt) {
  const int blk  = blockIdx.x;   // 0..1023
  const int bc   = blk & 255;    // same-XCD partners under %8 round-robin
  const int sb   = blk >> 8;     // 0..3
  const int tid  = threadIdx.x;
  const int lane = tid & 63;
  const int w    = tid >> 6;     // 0..2

  __shared__ __align__(16) unsigned char pool[27648];
  unsigned char* arenaA = pool;
  unsigned char* arenaB = pool + 13824;

  const int kb    = (lane >> 4) * 8;
  const int c16   = lane & 15;
  const int cc    = w * 16 + c16;       // 0..47
  const int rbase = (lane >> 4) * 4;

  // ================= PHASE 1: 12 slabs (n1 = sb*12 .. sb*12+11) =================
  {
    half8 t1h[3][2], t1l[3][2];
#pragma unroll
    for (int mt = 0; mt < 3; ++mt)
#pragma unroll
      for (int ks = 0; ks < 2; ++ks) {
        t1h[mt][ks] = *(const half8*)&T1frag[0][mt][ks][lane][0];
        t1l[mt][ks] = *(const half8*)&T1frag[1][mt][ks][lane][0];
      }
    half8 t2h[2], t2l[2];
#pragma unroll
    for (int ks = 0; ks < 2; ++ks) {
      t2h[ks] = *(const half8*)&T2frag[0][w][ks][lane][0];
      t2l[ks] = *(const half8*)&T2frag[1][w][ks][lane][0];
    }

    const int k2e  = tid % 24;
    const int k30e = (tid / 24) * 3;
    const int n1base = sb * 12;

    // prologue prefetch (g=0)
    float4 xr0, xr1, xr2;
    {
      const float4* g4 = (const float4*)(x + ((size_t)(bc * 48 + n1base)) * 2304);
      xr0 = g4[tid]; xr1 = g4[tid + 192]; xr2 = g4[tid + 384];
    }

    // Race audit (r11/r12 schedule, 12 iters):
    //  stage(g) writes arena[g&1]; prior readers GEMM2(g-1) all pre-b3(g-1);
    //    concurrent epilogue(g-1) reads the OTHER arena. OK.
    //  Udump(g) writes arena[1-(g&1)] post-b1(g); epilogue(g-1) D2-reads pre-b1(g). OK.
    //  D2dump(g) writes aX(g); GEMM1(g) X-reads all pre-b2(g). OK.
    for (int g = 0; g < 12; ++g) {
      const int n1 = n1base + g;
      unsigned char* aX = (g & 1) ? arenaB : arenaA;
      unsigned char* aU = (g & 1) ? arenaA : arenaB;
      _Float16* Xh = (_Float16*)aX;             // [48][72]
      _Float16* Xl = (_Float16*)(aX + 6912);
      float*    D2 = (float*)aX;                // [48][68] f32 view
      _Float16* Uh = (_Float16*)aU;
      _Float16* Ul = (_Float16*)(aU + 6912);

      // stage X from prefetched regs
      {
        const float4 fr[3] = {xr0, xr1, xr2};
#pragma unroll
        for (int jj = 0; jj < 3; ++jj) {
          const int i4 = tid + 192 * jj;             // 0..575
          const int r = i4 / 12, c4 = i4 % 12;
          const float4 f = fr[jj];
          const _Float16 h0 = (_Float16)f.x, h1 = (_Float16)f.y,
                         h2 = (_Float16)f.z, h3 = (_Float16)f.w;
          const half4v hv = {h0, h1, h2, h3};
          const half4v lv = {(_Float16)(f.x - (float)h0), (_Float16)(f.y - (float)h1),
                             (_Float16)(f.z - (float)h2), (_Float16)(f.w - (float)h3)};
          *(half4v*)&Xh[r * 72 + c4 * 4] = hv;
          *(half4v*)&Xl[r * 72 + c4 * 4] = lv;
        }
      }
      // zero X pad cols 48..63 (arena held D2/U junk)
      if (tid < 96) {
        _Float16* p = (tid < 48 ? Xh : Xl) + (tid % 48) * 72 + 48;
        *(half8*)&p[0] = (half8){};
        *(half8*)&p[8] = (half8){};
      }
      // prefetch next slab
      if (g < 11) {
        const float4* g4 = (const float4*)(x + ((size_t)(bc * 48 + n1 + 1)) * 2304);
        xr0 = g4[tid]; xr1 = g4[tid + 192]; xr2 = g4[tid + 384];
      }
      __syncthreads();   // b1: X staged

      // ---- GEMM1: D1 = T1 * X ----
      f32x4 acc0 = {}, acc1 = {}, acc2 = {};
#pragma unroll
      for (int ks = 0; ks < 2; ++ks) {
        const half8 bh = *(const half8*)&Xh[(w * 16 + c16) * 72 + ks * 32 + kb];
        const half8 bl = *(const half8*)&Xl[(w * 16 + c16) * 72 + ks * 32 + kb];
#pragma unroll
        for (int mt = 0; mt < 3; ++mt) {
          f32x4& acc = (mt == 0) ? acc0 : (mt == 1) ? acc1 : acc2;
          acc = __builtin_amdgcn_mfma_f32_16x16x32_f16(t1h[mt][ks], bh, acc, 0, 0, 0);
          acc = __builtin_amdgcn_mfma_f32_16x16x32_f16(t1h[mt][ks], bl, acc, 0, 0, 0);
          acc = __builtin_amdgcn_mfma_f32_16x16x32_f16(t1l[mt][ks], bh, acc, 0, 0, 0);
        }
      }

      // U dump
#pragma unroll
      for (int mt = 0; mt < 3; ++mt) {
        const int r0 = mt * 16 + (lane >> 4) * 4;
        const f32x4 acc = (mt == 0) ? acc0 : (mt == 1) ? acc1 : acc2;
#pragma unroll
        for (int r = 0; r < 4; ++r) {
          const float v = acc[r];
          const _Float16 h = (_Float16)v;
          Uh[(r0 + r) * 72 + cc] = h;
          Ul[(r0 + r) * 72 + cc] = (_Float16)(v - (float)h);
        }
      }
      // zero U pad cols 48..63
      if (tid < 96) {
        _Float16* p = (tid < 48 ? Uh : Ul) + (tid % 48) * 72 + 48;
        *(half8*)&p[0] = (half8){};
        *(half8*)&p[8] = (half8){};
      }
      __syncthreads();   // b2: U visible (and all X reads done)

      // ---- GEMM2: D2 = U * T2t ----
      f32x4 d20 = {}, d21 = {}, d22 = {};
#pragma unroll
      for (int ks = 0; ks < 2; ++ks) {
#pragma unroll
        for (int mt = 0; mt < 3; ++mt) {
          const half8 ah = *(const half8*)&Uh[(mt * 16 + c16) * 72 + ks * 32 + kb];
          const half8 al = *(const half8*)&Ul[(mt * 16 + c16) * 72 + ks * 32 + kb];
          f32x4& acc = (mt == 0) ? d20 : (mt == 1) ? d21 : d22;
          acc = __builtin_amdgcn_mfma_f32_16x16x32_f16(ah, t2h[ks], acc, 0, 0, 0);
          acc = __builtin_amdgcn_mfma_f32_16x16x32_f16(ah, t2l[ks], acc, 0, 0, 0);
          acc = __builtin_amdgcn_mfma_f32_16x16x32_f16(al, t2h[ks], acc, 0, 0, 0);
        }
      }

      // D2 dump into aX arena (X dead since b2)
#pragma unroll
      for (int mt = 0; mt < 3; ++mt) {
        const int r0 = mt * 16 + (lane >> 4) * 4;
        const f32x4 acc = (mt == 0) ? d20 : (mt == 1) ? d21 : d22;
#pragma unroll
        for (int r = 0; r < 4; ++r) D2[(r0 + r) * 68 + cc] = acc[r];
      }
      __syncthreads();   // b3: D2 visible (all U reads done)

      // epilogue: recombine -> V[bc][k3][n1][k2]  (overlaps next iter's stage)
      float2* Vp = V + (size_t)(bc * 24) * 1152 + (size_t)n1 * 24 + k2e;
#pragma unroll
      for (int q = 0; q < 3; ++q) {
        const int k3 = k30e + q;
        const float grr = D2[k3 * 68 + k2e];
        const float gis = D2[(k3 + 24) * 68 + k2e + 24];
        const float gir = D2[(k3 + 24) * 68 + k2e];
        const float grs = D2[k3 * 68 + k2e + 24];
        Vp[(size_t)k3 * 1152] = make_float2(grr + gis, gir - grs);
      }
      // no trailing barrier: next stage writes the OTHER arena.
    }
  }

  sync_bc4(cnt + bc);   // PHASE BOUNDARY 1->2: all 4 sub-blocks' V[bc] visible.

  // ================= PHASE 2: 6 k3-GEMMs (k3 = sb*6 .. sb*6+5) =================
  // N=24 real cols (cols 24..47 garbage: stale LDS; MFMA cols don't mix; cc>=24
  // threads never store).
  {
    float* Bb = (float*)pool;   // [col 0..47][kap 0..95] stride 100

    half8 kth[4][3], ktl[4][3];
#pragma unroll
    for (int mt = 0; mt < 4; ++mt)
#pragma unroll
      for (int ks = 0; ks < 3; ++ks) {
        kth[mt][ks] = *(const half8*)&TK2frag[0][mt][ks][lane][0];
        ktl[mt][ks] = *(const half8*)&TK2frag[1][mt][ks][lane][0];
      }

    const int k3base = sb * 6;

    // prologue prefetch: V[bc][k3base] slab
    float4 vr0, vr1, vr2;
    {
      const float4* g0 = (const float4*)(V + (size_t)(bc * 24 + k3base) * 1152);
      vr0 = g0[tid]; vr1 = g0[tid + 192]; vr2 = g0[tid + 384];
    }

    for (int q = 0; q < 6; ++q) {
      const int k3 = k3base + q;
      if (q) __syncthreads();   // prev iteration's Bb reads done

      // stage cols 0..23 from prefetched regs
      {
        const float4 fr[3] = {vr0, vr1, vr2};
#pragma unroll
        for (int jj = 0; jj < 3; ++jj) {
          const int r = tid + 192 * jj;     // 0..575 ; n1 = r/12, k2-pair = r%12
          const int n1 = r / 12, c4 = r % 12;
          const float4 f = fr[jj];
          float* bp = &Bb[(c4 * 2) * 100 + n1];
          bp[0]   = f.x;  bp[48]  = f.y;    // col 2*c4:   Vr[n1], Vi[n1]
          bp[100] = f.z;  bp[148] = f.w;    // col 2*c4+1
        }
      }
      // prefetch next k3 slab (within our range)
      if (q < 5) {
        const float4* g0 = (const float4*)(V + (size_t)(bc * 24 + k3 + 1) * 1152);
        vr0 = g0[tid]; vr1 = g0[tid + 192]; vr2 = g0[tid + 384];
      }
      __syncthreads();

      f32x4 a0 = {}, a1 = {}, a2 = {}, a3 = {};
#pragma unroll
      for (int ks = 0; ks < 3; ++ks) {
        const float4 q0 = *(const float4*)&Bb[cc * 100 + ks * 32 + kb];
        const float4 q1 = *(const float4*)&Bb[cc * 100 + ks * 32 + kb + 4];
        const float qf[8] = {q0.x, q0.y, q0.z, q0.w, q1.x, q1.y, q1.z, q1.w};
        half8 bh, bl;
        split8(qf, bh, bl);
#pragma unroll
        for (int mt = 0; mt < 4; ++mt) {
          f32x4& acc = (mt == 0) ? a0 : (mt == 1) ? a1 : (mt == 2) ? a2 : a3;
          acc = __builtin_amdgcn_mfma_f32_16x16x32_f16(kth[mt][ks], bh, acc, 0, 0, 0);
          acc = __builtin_amdgcn_mfma_f32_16x16x32_f16(kth[mt][ks], bl, acc, 0, 0, 0);
          acc = __builtin_amdgcn_mfma_f32_16x16x32_f16(ktl[mt][ks], bh, acc, 0, 0, 0);
        }
      }

      // epilogue: rows 0..31 = Wr, rows 32..63 = Wi -> W[bc][m1][k3][k2]
      if (cc < 24) {
        float2* wp = W + (size_t)bc * 18432 + (size_t)k3 * 24 + cc;
#pragma unroll
        for (int mt = 0; mt < 2; ++mt) {
          const f32x4 wr = (mt == 0) ? a0 : a1;
          const f32x4 wi = (mt == 0) ? a2 : a3;
#pragma unroll
          for (int r = 0; r < 4; ++r) {
            const int m1 = mt * 16 + rbase + r;
            wp[(size_t)m1 * 576] = make_float2(wr[r], wi[r]);
          }
        }
      }
    }
  }

  sync_bc4(cnt + 256 + bc);   // PHASE BOUNDARY 2->3: all 4 sub-blocks' W[bc] visible.

  // ================= PHASE 3: 8 m1-GEMMs (m1 = sb*8 .. sb*8+7) =================
  // Waves 0-1 compute; wave 2 helps stage only (wave-uniform guards). All waves barrier.
  {
    float* Bt = (float*)pool;            // [col=k3 0..31][kap 0..67]
    float* Zb = (float*)(pool + 8704);   // [m2 0..31][kap 0..67]

    half8 mbh[4][2], mbl[4][2];
#pragma unroll
    for (int mt = 0; mt < 4; ++mt)
#pragma unroll
      for (int ks = 0; ks < 2; ++ks) {
        mbh[mt][ks] = *(const half8*)&MB2frag[0][mt][ks][lane][0];
        mbl[mt][ks] = *(const half8*)&MB2frag[1][mt][ks][lane][0];
      }
    const int wn = (w < 2) ? w : 0;      // clamp table index for wave 2 (unused)
    half8 tb3h[2], tb3l[2];
#pragma unroll
    for (int ks = 0; ks < 2; ++ks) {
      tb3h[ks] = *(const half8*)&TB3frag[0][wn][ks][lane][0];
      tb3l[ks] = *(const half8*)&TB3frag[1][wn][ks][lane][0];
    }

    // zero pad regions ONCE (pool held Bb junk); fenced by b1 of first iter
    for (int i = tid; i < 8 * 68; i += 192)  Bt[(24 + i / 68) * 68 + (i % 68)] = 0.f;
    for (int i = tid; i < 24 * 20; i += 192) Bt[(i / 20) * 68 + 48 + (i % 20)] = 0.f;
    for (int i = tid; i < 32 * 20; i += 192) Zb[(i / 20) * 68 + 48 + (i % 20)] = 0.f;

    const int m1base = sb * 8;

    // prologue prefetch: W[bc][m1base] row (288 contiguous float4)
    float4 vr0, vr1;
    {
      const float4* g4 = (const float4*)(W + (size_t)bc * 18432 + (size_t)m1base * 576);
      vr0 = g4[tid];
      if (tid < 96) vr1 = g4[tid + 192];
    }

    // Race audit (r12 schedule): stage(q) writes Bt, readers GEMM1(q-1) all
    // pre-b2(q-1). relayout(q) writes Zb post-b1(q), readers GEMM2(q-1) all
    // pre-b1(q) per-wave program order. GEMM2(q) reads Zb written pre-b2(q).
    for (int q = 0; q < 8; ++q) {
      const int m1 = m1base + q;

      // stage Bt from prefetched regs (288 float4 over 192 threads)
      {
#pragma unroll
        for (int jj = 0; jj < 2; ++jj) {
          const int i4 = tid + 192 * jj;
          if (jj == 0 || tid < 96) {
            const int k3 = i4 / 12, c4 = i4 % 12;
            const float4 f = (jj == 0) ? vr0 : vr1;
            Bt[k3 * 68 + 2 * c4]          = f.x;
            Bt[k3 * 68 + 24 + 2 * c4]     = f.y;
            Bt[k3 * 68 + 2 * c4 + 1]      = f.z;
            Bt[k3 * 68 + 24 + 2 * c4 + 1] = f.w;
          }
        }
      }
      // prefetch next m1 (within our range)
      if (q < 7) {
        const float4* g4 = (const float4*)(W + (size_t)bc * 18432 + (size_t)(m1 + 1) * 576);
        vr0 = g4[tid];
        if (tid < 96) vr1 = g4[tid + 192];
      }
      __syncthreads();   // b1: Bt staged (and prev GEMM2's Zb reads done)

      if (w < 2) {
        // GEMM1: [Zr;Zi](64 x k3) = MB2 * [Wr;Wi]
        f32x4 z0 = {}, z1 = {}, z2 = {}, z3 = {};
#pragma unroll
        for (int ks = 0; ks < 2; ++ks) {
          const float4 q0 = *(const float4*)&Bt[cc * 68 + ks * 32 + kb];
          const float4 q1 = *(const float4*)&Bt[cc * 68 + ks * 32 + kb + 4];
          const float qf[8] = {q0.x, q0.y, q0.z, q0.w, q1.x, q1.y, q1.z, q1.w};
          half8 bh, bl;
          split8(qf, bh, bl);
#pragma unroll
          for (int mt = 0; mt < 4; ++mt) {
            f32x4& acc = (mt == 0) ? z0 : (mt == 1) ? z1 : (mt == 2) ? z2 : z3;
            acc = __builtin_amdgcn_mfma_f32_16x16x32_f16(mbh[mt][ks], bh, acc, 0, 0, 0);
            acc = __builtin_amdgcn_mfma_f32_16x16x32_f16(mbh[mt][ks], bl, acc, 0, 0, 0);
            acc = __builtin_amdgcn_mfma_f32_16x16x32_f16(mbl[mt][ks], bh, acc, 0, 0, 0);
          }
        }
        // relayout: Zb[m2][k3] = Zr, Zb[m2][24+k3] = Zi
        if (cc < 24) {
#pragma unroll
          for (int mt = 0; mt < 4; ++mt) {
            const f32x4 acc = (mt == 0) ? z0 : (mt == 1) ? z1 : (mt == 2) ? z2 : z3;
            const int row0 = mt * 16 + rbase;
#pragma unroll
            for (int r = 0; r < 4; ++r) {
              const int row = row0 + r;
              if (row < 32) Zb[row * 68 + cc]              = acc[r];
              else          Zb[(row - 32) * 68 + 24 + cc]  = acc[r];
            }
          }
        }
      }
      __syncthreads();   // b2: Zb visible (and all Bt reads done)

      if (w < 2) {
        // GEMM2: out(32x32) = Z(32 x 48p64) * TB3
        f32x4 o0 = {}, o1 = {};
#pragma unroll
        for (int ks = 0; ks < 2; ++ks) {
#pragma unroll
          for (int mt = 0; mt < 2; ++mt) {
            const float4 q0 = *(const float4*)&Zb[(mt * 16 + c16) * 68 + ks * 32 + kb];
            const float4 q1 = *(const float4*)&Zb[(mt * 16 + c16) * 68 + ks * 32 + kb + 4];
            const float qf[8] = {q0.x, q0.y, q0.z, q0.w, q1.x, q1.y, q1.z, q1.w};
            half8 ah, al;
            split8(qf, ah, al);
            f32x4& acc = (mt == 0) ? o0 : o1;
            acc = __builtin_amdgcn_mfma_f32_16x16x32_f16(ah, tb3h[ks], acc, 0, 0, 0);
            acc = __builtin_amdgcn_mfma_f32_16x16x32_f16(ah, tb3l[ks], acc, 0, 0, 0);
            acc = __builtin_amdgcn_mfma_f32_16x16x32_f16(al, tb3h[ks], acc, 0, 0, 0);
          }
        }
        float* op = out + (size_t)(bc * 32 + m1) * 1024;
#pragma unroll
        for (int mt = 0; mt < 2; ++mt) {
          const f32x4 acc = (mt == 0) ? o0 : o1;
#pragma unroll
          for (int r = 0; r < 4; ++r) {
            const int m2 = mt * 16 + rbase + r;
            op[m2 * 32 + cc] = acc[r] * NORM_F;
          }
        }
      }
    }
  }

  // lazy-init flag: strictly after k_init_tw in stream order.
  if (tid == 0 && blk == 0) g_twdone = 1;
}

extern "C" void kernel_launch(void* const* d_in, const int* in_sizes, int n_in,
                              void* d_out, int out_size, void* d_ws, size_t ws_size,
                              hipStream_t stream) {
  const float* x = (const float*)d_in[0];
  float* out = (float*)d_out;
  float2* V = (float2*)d_ws;                                   // 56,623,104 B
  float2* W = (float2*)((char*)d_ws + 56623104);               // 37,748,736 B
  int*    cnt = (int*)((char*)d_ws + 94371840);                // int[2][256]

  k_init_tw <<<dim3(60),   dim3(256), 0, stream>>>(cnt);
  k_mono    <<<dim3(1024), dim3(192), 0, stream>>>(x, V, W, out, cnt);
}

// Round 5
// 146.932 us; speedup vs baseline: 1.5069x; 1.5069x over previous
//
#include <hip/hip_runtime.h>
#include <math.h>

// SpectralPooling: out = Re(ifft3_32(pad32(crop24(Re(fft3_48(x))))))  per (b,c) volume.
// bc = 256 volumes of 48^3 fp32 -> 256 x 32^3 fp32.
//
// r14: r13 with the REGISTER CEILING FIXED. r13's launch_bounds(192,4) forced
// VGPR 108->64 -> massive scratch spills (FETCH +80MB, WRITE +87MB, MfmaUtil 7%).
// launch_bounds(192,3) = 3 waves/SIMD = 12 waves/CU = exactly 4 blocks/CU, VGPR
// cap ~170 >= 108 -> no spills. Co-residency: LDS 27.6KB -> 5 blocks/CU, VGPR 108
// -> 5 blocks/CU; capacity 1280 >= grid 1024 (r13 empirically completed -> sync ok).
// Everything else identical to r13 (single-variable experiment).
//  phase1 (12 slabs/sb): D1 = T1*X ; D2 = D1*T2t ; recombine -> V[bc]
//  phase2 (6 k3/sb):  [Wr;Wi](64x24) = M_comb(64x96) * [Vr;Vi](96x24) -> W[bc]
//  phase3 (8 m1/sb):  [Zr;Zi] = MB2*[Wr;Wi] ; out = Z*TB3
// Split-f16 everywhere: P = Ahi*Bhi + Ahi*Blo + Alo*Bhi (~22 mantissa bits).
//
// d_ws: float2 V[256][24][48][24] (56,623,104 B), float2 W[256][32][24][24]
//       (37,748,736 B), int cnt[2][256] at offset 94,371,840 (re-zeroed per launch).

#define TWO_PI_48 0.13089969389957470f
#define TWO_PI_32 0.19634954084936207f
#define NORM_F    1.6611664e-05f         // 1/(48^1.5 * 32^1.5)

typedef _Float16 half8  __attribute__((ext_vector_type(8)));
typedef _Float16 half4v __attribute__((ext_vector_type(4)));
typedef float    f32x4  __attribute__((ext_vector_type(4)));

// Frag-layout tables: [hi/lo][tile][kstep][lane][j]
// A-frag element = A[tile*16 + (l&15)][ks*32 + (l>>4)*8 + j]
// B-frag element = B[ks*32 + (l>>4)*8 + j][tile*16 + (l&15)]
__device__ _Float16 T1frag[2][3][2][64][8];
__device__ _Float16 T2frag[2][3][2][64][8];
__device__ __align__(16) _Float16 TK2frag[2][4][3][64][8];  // M_comb 64x96
__device__ __align__(16) _Float16 MB2frag[2][4][2][64][8];  // 64x48 (pad 64)
__device__ __align__(16) _Float16 TB3frag[2][2][2][64][8];  // 48(pad64)x32

__device__ int g_twdone = 0;   // lazy-init flag (module-lifetime, set post-init)

__global__ void k_init_tw(int* __restrict__ cnt) {
  const int idx = blockIdx.x * 256 + threadIdx.x;   // 0..15359
  if (idx < 512) cnt[idx] = 0;                      // re-zero sync counters EVERY launch
  if (g_twdone) return;                             // tables already built (pure consts)
  if (idx < 3072) {                                 // K1 tables (verified r5)
    const int j  = idx & 7;
    const int l  = (idx >> 3) & 63;
    const int ks = (idx >> 9) & 1;
    const int t  = idx >> 10;
    const int k  = ks * 32 + (l >> 4) * 8 + j;
    {
      const int m = t * 16 + (l & 15);
      float v = 0.f;
      if (k < 48) {
        const float a = (float)(((m % 24) * k) % 48) * TWO_PI_48;
        v = (m < 24) ? cosf(a) : -sinf(a);
      }
      const _Float16 h = (_Float16)v;
      T1frag[0][t][ks][l][j] = h;
      T1frag[1][t][ks][l][j] = (_Float16)(v - (float)h);
    }
    {
      const int c = t * 16 + (l & 15);
      float v = 0.f;
      if (k < 48) {
        const float a = (float)(((c % 24) * k) % 48) * TWO_PI_48;
        v = (c < 24) ? cosf(a) : sinf(a);
      }
      const _Float16 h = (_Float16)v;
      T2frag[0][t][ks][l][j] = h;
      T2frag[1][t][ks][l][j] = (_Float16)(v - (float)h);
    }
  } else if (idx < 3072 + 6144) {                   // K2: M_comb (A3+B1 fused)
    const int local = idx - 3072;
    const int j = local & 7, l = (local >> 3) & 63;
    const int rest = local >> 9;                    // 0..11
    const int ks = rest % 3, mt = rest / 3;
    const int m   = mt * 16 + (l & 15);             // 0..63
    const int kap = ks * 32 + (l >> 4) * 8 + j;     // 0..95
    const int n1  = kap % 48;
    const bool isVi = kap >= 48;
    const int m1  = m & 31;
    const bool isWi = m >= 32;
    float acc = 0.f;
    for (int k1 = 0; k1 < 24; ++k1) {
      float s32v, c32v, s48v, c48v;
      sincosf((float)((k1 * m1) % 32) * TWO_PI_32, &s32v, &c32v);
      sincosf((float)((k1 * n1) % 48) * TWO_PI_48, &s48v, &c48v);
      acc = fmaf(isWi ? s32v : c32v, isVi ? s48v : c48v, acc);
    }
    const _Float16 h = (_Float16)acc;
    TK2frag[0][mt][ks][l][j] = h;
    TK2frag[1][mt][ks][l][j] = (_Float16)(acc - (float)h);
  } else if (idx < 3072 + 6144 + 4096) {            // K3: MB2 (B2 A-matrix)
    const int local = idx - (3072 + 6144);
    const int j = local & 7, l = (local >> 3) & 63;
    const int rest = local >> 9;                    // 0..7
    const int ks = rest & 1, mt = rest >> 1;
    const int m   = mt * 16 + (l & 15);             // 0..63
    const int kap = ks * 32 + (l >> 4) * 8 + j;     // 0..63
    float v = 0.f;
    if (kap < 48) {
      const int k2 = kap % 24;
      const int m2 = m & 31;
      float s, c;
      sincosf((float)((k2 * m2) % 32) * TWO_PI_32, &s, &c);
      if (m < 32) v = (kap < 24) ? c : -s;   // Zr = sum Wr*c - Wi*s
      else        v = (kap < 24) ? s :  c;   // Zi = sum Wr*s + Wi*c
    }
    const _Float16 h = (_Float16)v;
    MB2frag[0][mt][ks][l][j] = h;
    MB2frag[1][mt][ks][l][j] = (_Float16)(v - (float)h);
  } else if (idx < 15360) {                         // K3: TB3 (B3 B-matrix)
    const int local = idx - (3072 + 6144 + 4096);
    const int j = local & 7, l = (local >> 3) & 63;
    const int rest = local >> 9;                    // 0..3
    const int ks = rest & 1, nt = rest >> 1;
    const int m3  = nt * 16 + (l & 15);             // col 0..31
    const int kap = ks * 32 + (l >> 4) * 8 + j;     // 0..63
    float v = 0.f;
    if (kap < 48) {
      const int k3 = kap % 24;
      float s, c;
      sincosf((float)((k3 * m3) % 32) * TWO_PI_32, &s, &c);
      v = (kap < 24) ? c : -s;               // out = sum Zr*c - Zi*s
    }
    const _Float16 h = (_Float16)v;
    TB3frag[0][nt][ks][l][j] = h;
    TB3frag[1][nt][ks][l][j] = (_Float16)(v - (float)h);
  }
}

__device__ inline void split8(const float* qf, half8& h, half8& lo) {
#pragma unroll
  for (int j = 0; j < 8; ++j) {
    const _Float16 hh = (_Float16)qf[j];
    h[j]  = hh;
    lo[j] = (_Float16)(qf[j] - (float)hh);
  }
}

// Per-bc 4-way arrive-and-spin sync. Release-add publishes this block's prior
// global writes; relaxed spin; single acquire load before partner data is read.
__device__ inline void sync_bc4(int* ctr) {
  __syncthreads();
  if (threadIdx.x == 0) {
    __hip_atomic_fetch_add(ctr, 1, __ATOMIC_RELEASE, __HIP_MEMORY_SCOPE_AGENT);
    while (__hip_atomic_load(ctr, __ATOMIC_RELAXED, __HIP_MEMORY_SCOPE_AGENT) < 4)
      __builtin_amdgcn_s_sleep(2);
    (void)__hip_atomic_load(ctr, __ATOMIC_ACQUIRE, __HIP_MEMORY_SCOPE_AGENT);
  }
  __syncthreads();
}

// ---------------- mono kernel: 4 sub-blocks per bc, 192 threads ----------------
// LDS pool aliasing (sequential phases, barrier-fenced):
//   phase1: arenaA = pool[0:13824], arenaB = pool[13824:27648]  (ping-pong X/D2 vs U)
//   phase2: Bb = (float*)pool, 48*100*4 = 19200 B
//   phase3: Bt = (float*)pool (8704 B), Zb = (float*)(pool+8704) (8704 B)
__global__ __launch_bounds__(192, 3) void k_mono(const float* __restrict__ x,
                                                 float2* __restrict__ V,
                                                 float2* __restrict__ W,
                                                 float* __restrict__ out,
                                                 int* __restrict__ cnt) {
  const int blk  = blockIdx.x;   // 0..1023
  const int bc   = blk & 255;    // same-XCD partners under %8 round-robin
  const int sb   = blk >> 8;     // 0..3
  const int tid  = threadIdx.x;
  const int lane = tid & 63;
  const int w    = tid >> 6;     // 0..2

  __shared__ __align__(16) unsigned char pool[27648];
  unsigned char* arenaA = pool;
  unsigned char* arenaB = pool + 13824;

  const int kb    = (lane >> 4) * 8;
  const int c16   = lane & 15;
  const int cc    = w * 16 + c16;       // 0..47
  const int rbase = (lane >> 4) * 4;

  // ================= PHASE 1: 12 slabs (n1 = sb*12 .. sb*12+11) =================
  {
    half8 t1h[3][2], t1l[3][2];
#pragma unroll
    for (int mt = 0; mt < 3; ++mt)
#pragma unroll
      for (int ks = 0; ks < 2; ++ks) {
        t1h[mt][ks] = *(const half8*)&T1frag[0][mt][ks][lane][0];
        t1l[mt][ks] = *(const half8*)&T1frag[1][mt][ks][lane][0];
      }
    half8 t2h[2], t2l[2];
#pragma unroll
    for (int ks = 0; ks < 2; ++ks) {
      t2h[ks] = *(const half8*)&T2frag[0][w][ks][lane][0];
      t2l[ks] = *(const half8*)&T2frag[1][w][ks][lane][0];
    }

    const int k2e  = tid % 24;
    const int k30e = (tid / 24) * 3;
    const int n1base = sb * 12;

    // prologue prefetch (g=0)
    float4 xr0, xr1, xr2;
    {
      const float4* g4 = (const float4*)(x + ((size_t)(bc * 48 + n1base)) * 2304);
      xr0 = g4[tid]; xr1 = g4[tid + 192]; xr2 = g4[tid + 384];
    }

    // Race audit (r11/r12 schedule, 12 iters):
    //  stage(g) writes arena[g&1]; prior readers GEMM2(g-1) all pre-b3(g-1);
    //    concurrent epilogue(g-1) reads the OTHER arena. OK.
    //  Udump(g) writes arena[1-(g&1)] post-b1(g); epilogue(g-1) D2-reads pre-b1(g). OK.
    //  D2dump(g) writes aX(g); GEMM1(g) X-reads all pre-b2(g). OK.
    for (int g = 0; g < 12; ++g) {
      const int n1 = n1base + g;
      unsigned char* aX = (g & 1) ? arenaB : arenaA;
      unsigned char* aU = (g & 1) ? arenaA : arenaB;
      _Float16* Xh = (_Float16*)aX;             // [48][72]
      _Float16* Xl = (_Float16*)(aX + 6912);
      float*    D2 = (float*)aX;                // [48][68] f32 view
      _Float16* Uh = (_Float16*)aU;
      _Float16* Ul = (_Float16*)(aU + 6912);

      // stage X from prefetched regs
      {
        const float4 fr[3] = {xr0, xr1, xr2};
#pragma unroll
        for (int jj = 0; jj < 3; ++jj) {
          const int i4 = tid + 192 * jj;             // 0..575
          const int r = i4 / 12, c4 = i4 % 12;
          const float4 f = fr[jj];
          const _Float16 h0 = (_Float16)f.x, h1 = (_Float16)f.y,
                         h2 = (_Float16)f.z, h3 = (_Float16)f.w;
          const half4v hv = {h0, h1, h2, h3};
          const half4v lv = {(_Float16)(f.x - (float)h0), (_Float16)(f.y - (float)h1),
                             (_Float16)(f.z - (float)h2), (_Float16)(f.w - (float)h3)};
          *(half4v*)&Xh[r * 72 + c4 * 4] = hv;
          *(half4v*)&Xl[r * 72 + c4 * 4] = lv;
        }
      }
      // zero X pad cols 48..63 (arena held D2/U junk)
      if (tid < 96) {
        _Float16* p = (tid < 48 ? Xh : Xl) + (tid % 48) * 72 + 48;
        *(half8*)&p[0] = (half8){};
        *(half8*)&p[8] = (half8){};
      }
      // prefetch next slab
      if (g < 11) {
        const float4* g4 = (const float4*)(x + ((size_t)(bc * 48 + n1 + 1)) * 2304);
        xr0 = g4[tid]; xr1 = g4[tid + 192]; xr2 = g4[tid + 384];
      }
      __syncthreads();   // b1: X staged

      // ---- GEMM1: D1 = T1 * X ----
      f32x4 acc0 = {}, acc1 = {}, acc2 = {};
#pragma unroll
      for (int ks = 0; ks < 2; ++ks) {
        const half8 bh = *(const half8*)&Xh[(w * 16 + c16) * 72 + ks * 32 + kb];
        const half8 bl = *(const half8*)&Xl[(w * 16 + c16) * 72 + ks * 32 + kb];
#pragma unroll
        for (int mt = 0; mt < 3; ++mt) {
          f32x4& acc = (mt == 0) ? acc0 : (mt == 1) ? acc1 : acc2;
          acc = __builtin_amdgcn_mfma_f32_16x16x32_f16(t1h[mt][ks], bh, acc, 0, 0, 0);
          acc = __builtin_amdgcn_mfma_f32_16x16x32_f16(t1h[mt][ks], bl, acc, 0, 0, 0);
          acc = __builtin_amdgcn_mfma_f32_16x16x32_f16(t1l[mt][ks], bh, acc, 0, 0, 0);
        }
      }

      // U dump
#pragma unroll
      for (int mt = 0; mt < 3; ++mt) {
        const int r0 = mt * 16 + (lane >> 4) * 4;
        const f32x4 acc = (mt == 0) ? acc0 : (mt == 1) ? acc1 : acc2;
#pragma unroll
        for (int r = 0; r < 4; ++r) {
          const float v = acc[r];
          const _Float16 h = (_Float16)v;
          Uh[(r0 + r) * 72 + cc] = h;
          Ul[(r0 + r) * 72 + cc] = (_Float16)(v - (float)h);
        }
      }
      // zero U pad cols 48..63
      if (tid < 96) {
        _Float16* p = (tid < 48 ? Uh : Ul) + (tid % 48) * 72 + 48;
        *(half8*)&p[0] = (half8){};
        *(half8*)&p[8] = (half8){};
      }
      __syncthreads();   // b2: U visible (and all X reads done)

      // ---- GEMM2: D2 = U * T2t ----
      f32x4 d20 = {}, d21 = {}, d22 = {};
#pragma unroll
      for (int ks = 0; ks < 2; ++ks) {
#pragma unroll
        for (int mt = 0; mt < 3; ++mt) {
          const half8 ah = *(const half8*)&Uh[(mt * 16 + c16) * 72 + ks * 32 + kb];
          const half8 al = *(const half8*)&Ul[(mt * 16 + c16) * 72 + ks * 32 + kb];
          f32x4& acc = (mt == 0) ? d20 : (mt == 1) ? d21 : d22;
          acc = __builtin_amdgcn_mfma_f32_16x16x32_f16(ah, t2h[ks], acc, 0, 0, 0);
          acc = __builtin_amdgcn_mfma_f32_16x16x32_f16(ah, t2l[ks], acc, 0, 0, 0);
          acc = __builtin_amdgcn_mfma_f32_16x16x32_f16(al, t2h[ks], acc, 0, 0, 0);
        }
      }

      // D2 dump into aX arena (X dead since b2)
#pragma unroll
      for (int mt = 0; mt < 3; ++mt) {
        const int r0 = mt * 16 + (lane >> 4) * 4;
        const f32x4 acc = (mt == 0) ? d20 : (mt == 1) ? d21 : d22;
#pragma unroll
        for (int r = 0; r < 4; ++r) D2[(r0 + r) * 68 + cc] = acc[r];
      }
      __syncthreads();   // b3: D2 visible (all U reads done)

      // epilogue: recombine -> V[bc][k3][n1][k2]  (overlaps next iter's stage)
      float2* Vp = V + (size_t)(bc * 24) * 1152 + (size_t)n1 * 24 + k2e;
#pragma unroll
      for (int q = 0; q < 3; ++q) {
        const int k3 = k30e + q;
        const float grr = D2[k3 * 68 + k2e];
        const float gis = D2[(k3 + 24) * 68 + k2e + 24];
        const float gir = D2[(k3 + 24) * 68 + k2e];
        const float grs = D2[k3 * 68 + k2e + 24];
        Vp[(size_t)k3 * 1152] = make_float2(grr + gis, gir - grs);
      }
      // no trailing barrier: next stage writes the OTHER arena.
    }
  }

  sync_bc4(cnt + bc);   // PHASE BOUNDARY 1->2: all 4 sub-blocks' V[bc] visible.

  // ================= PHASE 2: 6 k3-GEMMs (k3 = sb*6 .. sb*6+5) =================
  // N=24 real cols (cols 24..47 garbage: stale LDS; MFMA cols don't mix; cc>=24
  // threads never store).
  {
    float* Bb = (float*)pool;   // [col 0..47][kap 0..95] stride 100

    half8 kth[4][3], ktl[4][3];
#pragma unroll
    for (int mt = 0; mt < 4; ++mt)
#pragma unroll
      for (int ks = 0; ks < 3; ++ks) {
        kth[mt][ks] = *(const half8*)&TK2frag[0][mt][ks][lane][0];
        ktl[mt][ks] = *(const half8*)&TK2frag[1][mt][ks][lane][0];
      }

    const int k3base = sb * 6;

    // prologue prefetch: V[bc][k3base] slab
    float4 vr0, vr1, vr2;
    {
      const float4* g0 = (const float4*)(V + (size_t)(bc * 24 + k3base) * 1152);
      vr0 = g0[tid]; vr1 = g0[tid + 192]; vr2 = g0[tid + 384];
    }

    for (int q = 0; q < 6; ++q) {
      const int k3 = k3base + q;
      if (q) __syncthreads();   // prev iteration's Bb reads done

      // stage cols 0..23 from prefetched regs
      {
        const float4 fr[3] = {vr0, vr1, vr2};
#pragma unroll
        for (int jj = 0; jj < 3; ++jj) {
          const int r = tid + 192 * jj;     // 0..575 ; n1 = r/12, k2-pair = r%12
          const int n1 = r / 12, c4 = r % 12;
          const float4 f = fr[jj];
          float* bp = &Bb[(c4 * 2) * 100 + n1];
          bp[0]   = f.x;  bp[48]  = f.y;    // col 2*c4:   Vr[n1], Vi[n1]
          bp[100] = f.z;  bp[148] = f.w;    // col 2*c4+1
        }
      }
      // prefetch next k3 slab (within our range)
      if (q < 5) {
        const float4* g0 = (const float4*)(V + (size_t)(bc * 24 + k3 + 1) * 1152);
        vr0 = g0[tid]; vr1 = g0[tid + 192]; vr2 = g0[tid + 384];
      }
      __syncthreads();

      f32x4 a0 = {}, a1 = {}, a2 = {}, a3 = {};
#pragma unroll
      for (int ks = 0; ks < 3; ++ks) {
        const float4 q0 = *(const float4*)&Bb[cc * 100 + ks * 32 + kb];
        const float4 q1 = *(const float4*)&Bb[cc * 100 + ks * 32 + kb + 4];
        const float qf[8] = {q0.x, q0.y, q0.z, q0.w, q1.x, q1.y, q1.z, q1.w};
        half8 bh, bl;
        split8(qf, bh, bl);
#pragma unroll
        for (int mt = 0; mt < 4; ++mt) {
          f32x4& acc = (mt == 0) ? a0 : (mt == 1) ? a1 : (mt == 2) ? a2 : a3;
          acc = __builtin_amdgcn_mfma_f32_16x16x32_f16(kth[mt][ks], bh, acc, 0, 0, 0);
          acc = __builtin_amdgcn_mfma_f32_16x16x32_f16(kth[mt][ks], bl, acc, 0, 0, 0);
          acc = __builtin_amdgcn_mfma_f32_16x16x32_f16(ktl[mt][ks], bh, acc, 0, 0, 0);
        }
      }

      // epilogue: rows 0..31 = Wr, rows 32..63 = Wi -> W[bc][m1][k3][k2]
      if (cc < 24) {
        float2* wp = W + (size_t)bc * 18432 + (size_t)k3 * 24 + cc;
#pragma unroll
        for (int mt = 0; mt < 2; ++mt) {
          const f32x4 wr = (mt == 0) ? a0 : a1;
          const f32x4 wi = (mt == 0) ? a2 : a3;
#pragma unroll
          for (int r = 0; r < 4; ++r) {
            const int m1 = mt * 16 + rbase + r;
            wp[(size_t)m1 * 576] = make_float2(wr[r], wi[r]);
          }
        }
      }
    }
  }

  sync_bc4(cnt + 256 + bc);   // PHASE BOUNDARY 2->3: all 4 sub-blocks' W[bc] visible.

  // ================= PHASE 3: 8 m1-GEMMs (m1 = sb*8 .. sb*8+7) =================
  // Waves 0-1 compute; wave 2 helps stage only (wave-uniform guards). All waves barrier.
  {
    float* Bt = (float*)pool;            // [col=k3 0..31][kap 0..67]
    float* Zb = (float*)(pool + 8704);   // [m2 0..31][kap 0..67]

    half8 mbh[4][2], mbl[4][2];
#pragma unroll
    for (int mt = 0; mt < 4; ++mt)
#pragma unroll
      for (int ks = 0; ks < 2; ++ks) {
        mbh[mt][ks] = *(const half8*)&MB2frag[0][mt][ks][lane][0];
        mbl[mt][ks] = *(const half8*)&MB2frag[1][mt][ks][lane][0];
      }
    const int wn = (w < 2) ? w : 0;      // clamp table index for wave 2 (unused)
    half8 tb3h[2], tb3l[2];
#pragma unroll
    for (int ks = 0; ks < 2; ++ks) {
      tb3h[ks] = *(const half8*)&TB3frag[0][wn][ks][lane][0];
      tb3l[ks] = *(const half8*)&TB3frag[1][wn][ks][lane][0];
    }

    // zero pad regions ONCE (pool held Bb junk); fenced by b1 of first iter
    for (int i = tid; i < 8 * 68; i += 192)  Bt[(24 + i / 68) * 68 + (i % 68)] = 0.f;
    for (int i = tid; i < 24 * 20; i += 192) Bt[(i / 20) * 68 + 48 + (i % 20)] = 0.f;
    for (int i = tid; i < 32 * 20; i += 192) Zb[(i / 20) * 68 + 48 + (i % 20)] = 0.f;

    const int m1base = sb * 8;

    // prologue prefetch: W[bc][m1base] row (288 contiguous float4)
    float4 vr0, vr1;
    {
      const float4* g4 = (const float4*)(W + (size_t)bc * 18432 + (size_t)m1base * 576);
      vr0 = g4[tid];
      if (tid < 96) vr1 = g4[tid + 192];
    }

    // Race audit (r12 schedule): stage(q) writes Bt, readers GEMM1(q-1) all
    // pre-b2(q-1). relayout(q) writes Zb post-b1(q), readers GEMM2(q-1) all
    // pre-b1(q) per-wave program order. GEMM2(q) reads Zb written pre-b2(q).
    for (int q = 0; q < 8; ++q) {
      const int m1 = m1base + q;

      // stage Bt from prefetched regs (288 float4 over 192 threads)
      {
#pragma unroll
        for (int jj = 0; jj < 2; ++jj) {
          const int i4 = tid + 192 * jj;
          if (jj == 0 || tid < 96) {
            const int k3 = i4 / 12, c4 = i4 % 12;
            const float4 f = (jj == 0) ? vr0 : vr1;
            Bt[k3 * 68 + 2 * c4]          = f.x;
            Bt[k3 * 68 + 24 + 2 * c4]     = f.y;
            Bt[k3 * 68 + 2 * c4 + 1]      = f.z;
            Bt[k3 * 68 + 24 + 2 * c4 + 1] = f.w;
          }
        }
      }
      // prefetch next m1 (within our range)
      if (q < 7) {
        const float4* g4 = (const float4*)(W + (size_t)bc * 18432 + (size_t)(m1 + 1) * 576);
        vr0 = g4[tid];
        if (tid < 96) vr1 = g4[tid + 192];
      }
      __syncthreads();   // b1: Bt staged (and prev GEMM2's Zb reads done)

      if (w < 2) {
        // GEMM1: [Zr;Zi](64 x k3) = MB2 * [Wr;Wi]
        f32x4 z0 = {}, z1 = {}, z2 = {}, z3 = {};
#pragma unroll
        for (int ks = 0; ks < 2; ++ks) {
          const float4 q0 = *(const float4*)&Bt[cc * 68 + ks * 32 + kb];
          const float4 q1 = *(const float4*)&Bt[cc * 68 + ks * 32 + kb + 4];
          const float qf[8] = {q0.x, q0.y, q0.z, q0.w, q1.x, q1.y, q1.z, q1.w};
          half8 bh, bl;
          split8(qf, bh, bl);
#pragma unroll
          for (int mt = 0; mt < 4; ++mt) {
            f32x4& acc = (mt == 0) ? z0 : (mt == 1) ? z1 : (mt == 2) ? z2 : z3;
            acc = __builtin_amdgcn_mfma_f32_16x16x32_f16(mbh[mt][ks], bh, acc, 0, 0, 0);
            acc = __builtin_amdgcn_mfma_f32_16x16x32_f16(mbh[mt][ks], bl, acc, 0, 0, 0);
            acc = __builtin_amdgcn_mfma_f32_16x16x32_f16(mbl[mt][ks], bh, acc, 0, 0, 0);
          }
        }
        // relayout: Zb[m2][k3] = Zr, Zb[m2][24+k3] = Zi
        if (cc < 24) {
#pragma unroll
          for (int mt = 0; mt < 4; ++mt) {
            const f32x4 acc = (mt == 0) ? z0 : (mt == 1) ? z1 : (mt == 2) ? z2 : z3;
            const int row0 = mt * 16 + rbase;
#pragma unroll
            for (int r = 0; r < 4; ++r) {
              const int row = row0 + r;
              if (row < 32) Zb[row * 68 + cc]              = acc[r];
              else          Zb[(row - 32) * 68 + 24 + cc]  = acc[r];
            }
          }
        }
      }
      __syncthreads();   // b2: Zb visible (and all Bt reads done)

      if (w < 2) {
        // GEMM2: out(32x32) = Z(32 x 48p64) * TB3
        f32x4 o0 = {}, o1 = {};
#pragma unroll
        for (int ks = 0; ks < 2; ++ks) {
#pragma unroll
          for (int mt = 0; mt < 2; ++mt) {
            const float4 q0 = *(const float4*)&Zb[(mt * 16 + c16) * 68 + ks * 32 + kb];
            const float4 q1 = *(const float4*)&Zb[(mt * 16 + c16) * 68 + ks * 32 + kb + 4];
            const float qf[8] = {q0.x, q0.y, q0.z, q0.w, q1.x, q1.y, q1.z, q1.w};
            half8 ah, al;
            split8(qf, ah, al);
            f32x4& acc = (mt == 0) ? o0 : o1;
            acc = __builtin_amdgcn_mfma_f32_16x16x32_f16(ah, tb3h[ks], acc, 0, 0, 0);
            acc = __builtin_amdgcn_mfma_f32_16x16x32_f16(ah, tb3l[ks], acc, 0, 0, 0);
            acc = __builtin_amdgcn_mfma_f32_16x16x32_f16(al, tb3h[ks], acc, 0, 0, 0);
          }
        }
        float* op = out + (size_t)(bc * 32 + m1) * 1024;
#pragma unroll
        for (int mt = 0; mt < 2; ++mt) {
          const f32x4 acc = (mt == 0) ? o0 : o1;
#pragma unroll
          for (int r = 0; r < 4; ++r) {
            const int m2 = mt * 16 + rbase + r;
            op[m2 * 32 + cc] = acc[r] * NORM_F;
          }
        }
      }
    }
  }

  // lazy-init flag: strictly after k_init_tw in stream order.
  if (tid == 0 && blk == 0) g_twdone = 1;
}

extern "C" void kernel_launch(void* const* d_in, const int* in_sizes, int n_in,
                              void* d_out, int out_size, void* d_ws, size_t ws_size,
                              hipStream_t stream) {
  const float* x = (const float*)d_in[0];
  float* out = (float*)d_out;
  float2* V = (float2*)d_ws;                                   // 56,623,104 B
  float2* W = (float2*)((char*)d_ws + 56623104);               // 37,748,736 B
  int*    cnt = (int*)((char*)d_ws + 94371840);                // int[2][256]

  k_init_tw <<<dim3(60),   dim3(256), 0, stream>>>(cnt);
  k_mono    <<<dim3(1024), dim3(192), 0, stream>>>(x, V, W, out, cnt);
}

// Round 6
// 100.001 us; speedup vs baseline: 2.2141x; 1.4693x over previous
//
#include <hip/hip_runtime.h>
#include <math.h>

// SpectralPooling: out = Re(ifft3_32(pad32(crop24(Re(fft3_48(x))))))  per (b,c) volume.
// bc = 256 volumes of 48^3 fp32 -> 256 x 32^3 fp32.
//
// r15: REVERT to r11 split pipeline (best verified 81.4us; mono/sync line r12-r14
// all worse) + ONE change: K1 blocks = 384 thr = TWO independent 3-wave groups,
// each running the verified r11 slab schedule on its own slab stream with private
// LDS arenas, sharing the block's barriers. Mechanism: K1 is latency-bound on its
// barrier chain (all pipes <15% across rounds); two slabs in flight per barrier
// phase halves barriers/slab and doubles independent work per stall point.
// LDS 4 arenas = 55296 B -> 2 blocks/CU = 12 waves/CU (same as before).
// K2/K3/init verbatim r11.
//  K1 (per bc, grid 12x256, 2 groups x 2 slabs): D1=T1*X ; D2=D1*T2t ; -> V
//  K2 (per k3, 2x bc-pair): [Wr;Wi](64x48) = M_comb(64x96) * [Vr;Vi](96x48) -> W
//  K3 (per m1, 2x bc): [Zr;Zi] = MB2*[Wr;Wi] ; out = Z*TB3
// Split-f16 everywhere: P = Ahi*Bhi + Ahi*Blo + Alo*Bhi (~22 mantissa bits).
//
// d_ws: float2 V[256][24][48][24] (56,623,104 B) then
//       float2 W[256][32][24][24] (37,748,736 B) at byte offset 56,623,104.

#define TWO_PI_48 0.13089969389957470f
#define TWO_PI_32 0.19634954084936207f
#define NORM_F    1.6611664e-05f         // 1/(48^1.5 * 32^1.5)

typedef _Float16 half8  __attribute__((ext_vector_type(8)));
typedef _Float16 half4v __attribute__((ext_vector_type(4)));
typedef float    f32x4  __attribute__((ext_vector_type(4)));

// Frag-layout tables: [hi/lo][tile][kstep][lane][j]
// A-frag element = A[tile*16 + (l&15)][ks*32 + (l>>4)*8 + j]
// B-frag element = B[ks*32 + (l>>4)*8 + j][tile*16 + (l&15)]
__device__ _Float16 T1frag[2][3][2][64][8];
__device__ _Float16 T2frag[2][3][2][64][8];
__device__ __align__(16) _Float16 TK2frag[2][4][3][64][8];  // M_comb 64x96
__device__ __align__(16) _Float16 MB2frag[2][4][2][64][8];  // 64x48 (pad 64)
__device__ __align__(16) _Float16 TB3frag[2][2][2][64][8];  // 48(pad64)x32

__device__ int g_twdone = 0;   // lazy-init flag (module-lifetime, set post-init)

__global__ void k_init_tw() {
  if (g_twdone) return;                             // tables already built (pure consts)
  const int idx = blockIdx.x * 256 + threadIdx.x;   // 0..15359
  if (idx < 3072) {                                 // K1 tables (verified r5)
    const int j  = idx & 7;
    const int l  = (idx >> 3) & 63;
    const int ks = (idx >> 9) & 1;
    const int t  = idx >> 10;
    const int k  = ks * 32 + (l >> 4) * 8 + j;
    {
      const int m = t * 16 + (l & 15);
      float v = 0.f;
      if (k < 48) {
        const float a = (float)(((m % 24) * k) % 48) * TWO_PI_48;
        v = (m < 24) ? cosf(a) : -sinf(a);
      }
      const _Float16 h = (_Float16)v;
      T1frag[0][t][ks][l][j] = h;
      T1frag[1][t][ks][l][j] = (_Float16)(v - (float)h);
    }
    {
      const int c = t * 16 + (l & 15);
      float v = 0.f;
      if (k < 48) {
        const float a = (float)(((c % 24) * k) % 48) * TWO_PI_48;
        v = (c < 24) ? cosf(a) : sinf(a);
      }
      const _Float16 h = (_Float16)v;
      T2frag[0][t][ks][l][j] = h;
      T2frag[1][t][ks][l][j] = (_Float16)(v - (float)h);
    }
  } else if (idx < 3072 + 6144) {                   // K2: M_comb (A3+B1 fused)
    const int local = idx - 3072;
    const int j = local & 7, l = (local >> 3) & 63;
    const int rest = local >> 9;                    // 0..11
    const int ks = rest % 3, mt = rest / 3;
    const int m   = mt * 16 + (l & 15);             // 0..63
    const int kap = ks * 32 + (l >> 4) * 8 + j;     // 0..95
    const int n1  = kap % 48;
    const bool isVi = kap >= 48;
    const int m1  = m & 31;
    const bool isWi = m >= 32;
    float acc = 0.f;
    for (int k1 = 0; k1 < 24; ++k1) {
      float s32v, c32v, s48v, c48v;
      sincosf((float)((k1 * m1) % 32) * TWO_PI_32, &s32v, &c32v);
      sincosf((float)((k1 * n1) % 48) * TWO_PI_48, &s48v, &c48v);
      acc = fmaf(isWi ? s32v : c32v, isVi ? s48v : c48v, acc);
    }
    const _Float16 h = (_Float16)acc;
    TK2frag[0][mt][ks][l][j] = h;
    TK2frag[1][mt][ks][l][j] = (_Float16)(acc - (float)h);
  } else if (idx < 3072 + 6144 + 4096) {            // K3: MB2 (B2 A-matrix)
    const int local = idx - (3072 + 6144);
    const int j = local & 7, l = (local >> 3) & 63;
    const int rest = local >> 9;                    // 0..7
    const int ks = rest & 1, mt = rest >> 1;
    const int m   = mt * 16 + (l & 15);             // 0..63
    const int kap = ks * 32 + (l >> 4) * 8 + j;     // 0..63
    float v = 0.f;
    if (kap < 48) {
      const int k2 = kap % 24;
      const int m2 = m & 31;
      float s, c;
      sincosf((float)((k2 * m2) % 32) * TWO_PI_32, &s, &c);
      if (m < 32) v = (kap < 24) ? c : -s;   // Zr = sum Wr*c - Wi*s
      else        v = (kap < 24) ? s :  c;   // Zi = sum Wr*s + Wi*c
    }
    const _Float16 h = (_Float16)v;
    MB2frag[0][mt][ks][l][j] = h;
    MB2frag[1][mt][ks][l][j] = (_Float16)(v - (float)h);
  } else if (idx < 15360) {                         // K3: TB3 (B3 B-matrix)
    const int local = idx - (3072 + 6144 + 4096);
    const int j = local & 7, l = (local >> 3) & 63;
    const int rest = local >> 9;                    // 0..3
    const int ks = rest & 1, nt = rest >> 1;
    const int m3  = nt * 16 + (l & 15);             // col 0..31
    const int kap = ks * 32 + (l >> 4) * 8 + j;     // 0..63
    float v = 0.f;
    if (kap < 48) {
      const int k3 = kap % 24;
      float s, c;
      sincosf((float)((k3 * m3) % 32) * TWO_PI_32, &s, &c);
      v = (kap < 24) ? c : -s;               // out = sum Zr*c - Zi*s
    }
    const _Float16 h = (_Float16)v;
    TB3frag[0][nt][ks][l][j] = h;
    TB3frag[1][nt][ks][l][j] = (_Float16)(v - (float)h);
  }
}

__device__ inline void split8(const float* qf, half8& h, half8& lo) {
#pragma unroll
  for (int j = 0; j < 8; ++j) {
    const _Float16 hh = (_Float16)qf[j];
    h[j]  = hh;
    lo[j] = (_Float16)(qf[j] - (float)hh);
  }
}

// ---------------- K1: A1 + A2 via MFMA (384 thr = 2 groups, grid 12 x 256) ----------------
// Each 3-wave group runs the verified r11 2-slab ping-pong schedule on its own
// slab stream (group grp handles n1 = bx*4 + grp*2 + {0,1}) with private arenas
// pool[grp*2], pool[grp*2+1]. Barriers are block-wide (sync both groups) — this
// only ADDS ordering vs the per-group r11 audit, so the r11 race audit holds:
//  stage(it) writes arena[grp*2 + (it&1)]; prior readers GEMM2(it-1) pre-b3(it-1),
//    epilogue(it-1) reads the other arena. OK.
//  Udump(it) writes arena[grp*2 + 1-(it&1)] post-b1(it); epilogue(it-1) D2-reads
//    are pre-b1(it) in program order. OK.
//  D2dump(it) writes X arena; GEMM1(it) X-reads all pre-b2(it). OK.
__global__ __launch_bounds__(384) void k_a12_mfma(const float* __restrict__ x,
                                                  float2* __restrict__ V) {
  const int bx   = blockIdx.x;   // 0..11 -> n1 = bx*4 + grp*2 + it
  const int bc   = blockIdx.y;   // 0..255
  const int tid  = threadIdx.x;  // 0..383
  const int grp  = tid / 192;    // 0..1 (wave-uniform: waves 0-2 grp0, 3-5 grp1)
  const int t    = tid % 192;    // r11's tid within the group
  const int lane = t & 63;
  const int w    = t >> 6;       // 0..2

  __shared__ __align__(16) unsigned char pool[55296];   // 4 arenas x 13824
  unsigned char* arena0 = pool + (size_t)grp * 27648;
  unsigned char* arena1 = arena0 + 13824;

  // hoist twiddle fragments into registers (loop-invariant)
  half8 t1h[3][2], t1l[3][2];
#pragma unroll
  for (int mt = 0; mt < 3; ++mt)
#pragma unroll
    for (int ks = 0; ks < 2; ++ks) {
      t1h[mt][ks] = *(const half8*)&T1frag[0][mt][ks][lane][0];
      t1l[mt][ks] = *(const half8*)&T1frag[1][mt][ks][lane][0];
    }
  half8 t2h[2], t2l[2];
#pragma unroll
  for (int ks = 0; ks < 2; ++ks) {
    t2h[ks] = *(const half8*)&T2frag[0][w][ks][lane][0];
    t2l[ks] = *(const half8*)&T2frag[1][w][ks][lane][0];
  }

  const int kb   = (lane >> 4) * 8;
  const int c16  = lane & 15;
  const int k2e  = t % 24;
  const int k30e = (t / 24) * 3;
  const int n1base = bx * 4 + grp * 2;

  // prologue prefetch (it=0)
  float4 xr0, xr1, xr2;
  {
    const float4* g4 = (const float4*)(x + ((size_t)(bc * 48 + n1base)) * 2304);
    xr0 = g4[t]; xr1 = g4[t + 192]; xr2 = g4[t + 384];
  }

#pragma unroll
  for (int it = 0; it < 2; ++it) {
    const int n1 = n1base + it;
    unsigned char* aX = (it == 0) ? arena0 : arena1;
    unsigned char* aU = (it == 0) ? arena1 : arena0;
    _Float16* Xh = (_Float16*)aX;             // [48][72]
    _Float16* Xl = (_Float16*)(aX + 6912);
    float*    D2 = (float*)aX;                // [48][68] f32 view
    _Float16* Uh = (_Float16*)aU;
    _Float16* Ul = (_Float16*)(aU + 6912);

    // stage X from prefetched regs (split once per element)
    {
      const float4 fr[3] = {xr0, xr1, xr2};
#pragma unroll
      for (int jj = 0; jj < 3; ++jj) {
        const int i4 = t + 192 * jj;               // 0..575
        const int r = i4 / 12, c4 = i4 % 12;
        const float4 f = fr[jj];
        const _Float16 h0 = (_Float16)f.x, h1 = (_Float16)f.y,
                       h2 = (_Float16)f.z, h3 = (_Float16)f.w;
        const half4v hv = {h0, h1, h2, h3};
        const half4v lv = {(_Float16)(f.x - (float)h0), (_Float16)(f.y - (float)h1),
                           (_Float16)(f.z - (float)h2), (_Float16)(f.w - (float)h3)};
        *(half4v*)&Xh[r * 72 + c4 * 4] = hv;
        *(half4v*)&Xl[r * 72 + c4 * 4] = lv;
      }
    }
    // zero X pad cols 48..63 (arena held U/D2 junk)
    if (t < 96) {
      _Float16* p = (t < 48 ? Xh : Xl) + (t % 48) * 72 + 48;
      *(half8*)&p[0] = (half8){};
      *(half8*)&p[8] = (half8){};
    }
    // prefetch next slab (in flight across the whole compute phase)
    if (it < 1) {
      const float4* g4 = (const float4*)(x + ((size_t)(bc * 48 + n1 + 1)) * 2304);
      xr0 = g4[t]; xr1 = g4[t + 192]; xr2 = g4[t + 384];
    }
    __syncthreads();   // b1: X staged (both groups)

    // ---- GEMM1: D1 = T1 * X ----
    f32x4 acc0 = {}, acc1 = {}, acc2 = {};
#pragma unroll
    for (int ks = 0; ks < 2; ++ks) {
      const half8 bh = *(const half8*)&Xh[(w * 16 + c16) * 72 + ks * 32 + kb];
      const half8 bl = *(const half8*)&Xl[(w * 16 + c16) * 72 + ks * 32 + kb];
#pragma unroll
      for (int mt = 0; mt < 3; ++mt) {
        f32x4& acc = (mt == 0) ? acc0 : (mt == 1) ? acc1 : acc2;
        acc = __builtin_amdgcn_mfma_f32_16x16x32_f16(t1h[mt][ks], bh, acc, 0, 0, 0);
        acc = __builtin_amdgcn_mfma_f32_16x16x32_f16(t1h[mt][ks], bl, acc, 0, 0, 0);
        acc = __builtin_amdgcn_mfma_f32_16x16x32_f16(t1l[mt][ks], bh, acc, 0, 0, 0);
      }
    }

    // U dump (own group's aU arena)
    {
      const int cc = w * 16 + c16;
#pragma unroll
      for (int mt = 0; mt < 3; ++mt) {
        const int r0 = mt * 16 + (lane >> 4) * 4;
        const f32x4 acc = (mt == 0) ? acc0 : (mt == 1) ? acc1 : acc2;
#pragma unroll
        for (int r = 0; r < 4; ++r) {
          const float v = acc[r];
          const _Float16 h = (_Float16)v;
          Uh[(r0 + r) * 72 + cc] = h;
          Ul[(r0 + r) * 72 + cc] = (_Float16)(v - (float)h);
        }
      }
    }
    // zero U pad cols 48..63 (arena was clobbered by X/D2 last iter)
    if (t < 96) {
      _Float16* p = (t < 48 ? Uh : Ul) + (t % 48) * 72 + 48;
      *(half8*)&p[0] = (half8){};
      *(half8*)&p[8] = (half8){};
    }
    __syncthreads();   // b2: U visible (and all X reads done)

    // ---- GEMM2: D2 = U * T2t ----
    f32x4 d20 = {}, d21 = {}, d22 = {};
#pragma unroll
    for (int ks = 0; ks < 2; ++ks) {
#pragma unroll
      for (int mt = 0; mt < 3; ++mt) {
        const half8 ah = *(const half8*)&Uh[(mt * 16 + c16) * 72 + ks * 32 + kb];
        const half8 al = *(const half8*)&Ul[(mt * 16 + c16) * 72 + ks * 32 + kb];
        f32x4& acc = (mt == 0) ? d20 : (mt == 1) ? d21 : d22;
        acc = __builtin_amdgcn_mfma_f32_16x16x32_f16(ah, t2h[ks], acc, 0, 0, 0);
        acc = __builtin_amdgcn_mfma_f32_16x16x32_f16(ah, t2l[ks], acc, 0, 0, 0);
        acc = __builtin_amdgcn_mfma_f32_16x16x32_f16(al, t2h[ks], acc, 0, 0, 0);
      }
    }

    // D2 dump into X arena (X dead since b2)
    {
      const int cc = w * 16 + c16;
#pragma unroll
      for (int mt = 0; mt < 3; ++mt) {
        const int r0 = mt * 16 + (lane >> 4) * 4;
        const f32x4 acc = (mt == 0) ? d20 : (mt == 1) ? d21 : d22;
#pragma unroll
        for (int r = 0; r < 4; ++r) D2[(r0 + r) * 68 + cc] = acc[r];
      }
    }
    __syncthreads();   // b3: D2 visible (and all U reads done -> aU free next iter)

    // epilogue: recombine -> V[bc][k3][n1][k2]  (overlaps next iter's stage)
    float2* Vp = V + (size_t)(bc * 24) * 1152 + (size_t)n1 * 24 + k2e;
#pragma unroll
    for (int q = 0; q < 3; ++q) {
      const int k3 = k30e + q;
      const float grr = D2[k3 * 68 + k2e];
      const float gis = D2[(k3 + 24) * 68 + k2e + 24];
      const float gir = D2[(k3 + 24) * 68 + k2e];
      const float grs = D2[k3 * 68 + k2e + 24];
      Vp[(size_t)k3 * 1152] = make_float2(grr + gis, gir - grs);
    }
    // no trailing barrier: next stage writes the OTHER arena.
  }
}

// ---------------- K2: A3+B1 fused MFMA GEMM (192 thr, grid 24 x 64, 2 bc-pairs/block) ----------------
// Writes W[bc][m1][k3][k2] (separate buffer, m1-major) so K3 reads are contiguous.
__global__ __launch_bounds__(192) void k2_mfma(const float2* __restrict__ V,
                                               float2* __restrict__ W) {
  const int k3   = blockIdx.x;    // 0..23
  const int byy  = blockIdx.y;    // 0..63 -> bcp = byy*2+g
  const int tid  = threadIdx.x;
  const int lane = tid & 63;
  const int w    = tid >> 6;      // 0..2

  __shared__ __align__(16) float Bb[48 * 100];  // [col=s*24+k2][kap 0..95]

  half8 kth[4][3], ktl[4][3];
#pragma unroll
  for (int mt = 0; mt < 4; ++mt)
#pragma unroll
    for (int ks = 0; ks < 3; ++ks) {
      kth[mt][ks] = *(const half8*)&TK2frag[0][mt][ks][lane][0];
      ktl[mt][ks] = *(const half8*)&TK2frag[1][mt][ks][lane][0];
    }

  const int kbase = (lane >> 4) * 8;
  const int c16   = lane & 15;
  const int cc    = w * 16 + c16;       // 0..47
  const int sE    = cc / 24, k2E = cc % 24;
  const int rbase = (lane >> 4) * 4;

  // prologue prefetch (g=0): 6 float4/thread; s = jj/3, r = tid + 192*(jj%3)
  float4 vr[6];
  {
    const float4* g0 = (const float4*)(V + ((size_t)((byy * 4 + 0) * 24 + k3)) * 1152);
    const float4* g1 = (const float4*)(V + ((size_t)((byy * 4 + 1) * 24 + k3)) * 1152);
#pragma unroll
    for (int jj = 0; jj < 6; ++jj)
      vr[jj] = (jj < 3 ? g0 : g1)[tid + 192 * (jj % 3)];
  }

  for (int g = 0; g < 2; ++g) {
    const int bcp = byy * 2 + g;

    if (g) __syncthreads();   // prev iteration's Bb reads done

    // stage from prefetched regs
#pragma unroll
    for (int jj = 0; jj < 6; ++jj) {
      const int s = jj / 3;
      const int r = tid + 192 * (jj % 3);     // 0..575 within slab
      const int n1 = r / 12, c4 = r % 12;
      const float4 f = vr[jj];
      float* bp = &Bb[(s * 24 + c4 * 2) * 100 + n1];
      bp[0]   = f.x;  bp[48]  = f.y;
      bp[100] = f.z;  bp[148] = f.w;
    }
    // prefetch next bc-pair
    if (g < 1) {
      const float4* g0 = (const float4*)(V + ((size_t)((bcp * 2 + 2) * 24 + k3)) * 1152);
      const float4* g1 = (const float4*)(V + ((size_t)((bcp * 2 + 3) * 24 + k3)) * 1152);
#pragma unroll
      for (int jj = 0; jj < 6; ++jj)
        vr[jj] = (jj < 3 ? g0 : g1)[tid + 192 * (jj % 3)];
    }
    __syncthreads();

    f32x4 a0 = {}, a1 = {}, a2 = {}, a3 = {};
#pragma unroll
    for (int ks = 0; ks < 3; ++ks) {
      const float4 q0 = *(const float4*)&Bb[cc * 100 + ks * 32 + kbase];
      const float4 q1 = *(const float4*)&Bb[cc * 100 + ks * 32 + kbase + 4];
      const float qf[8] = {q0.x, q0.y, q0.z, q0.w, q1.x, q1.y, q1.z, q1.w};
      half8 bh, bl;
      split8(qf, bh, bl);
#pragma unroll
      for (int mt = 0; mt < 4; ++mt) {
        f32x4& acc = (mt == 0) ? a0 : (mt == 1) ? a1 : (mt == 2) ? a2 : a3;
        acc = __builtin_amdgcn_mfma_f32_16x16x32_f16(kth[mt][ks], bh, acc, 0, 0, 0);
        acc = __builtin_amdgcn_mfma_f32_16x16x32_f16(kth[mt][ks], bl, acc, 0, 0, 0);
        acc = __builtin_amdgcn_mfma_f32_16x16x32_f16(ktl[mt][ks], bh, acc, 0, 0, 0);
      }
    }

    // epilogue: rows 0..31 = Wr, rows 32..63 = Wi -> W[bc][m1][k3][k2]
    const int bc = bcp * 2 + sE;
    float2* wp = W + (size_t)bc * 18432 + (size_t)k3 * 24 + k2E;
#pragma unroll
    for (int mt = 0; mt < 2; ++mt) {
      const f32x4 wr = (mt == 0) ? a0 : a1;
      const f32x4 wi = (mt == 0) ? a2 : a3;
#pragma unroll
      for (int r = 0; r < 4; ++r) {
        const int m1 = mt * 16 + rbase + r;
        wp[(size_t)m1 * 576] = make_float2(wr[r], wi[r]);
      }
    }
  }
}

// ---------------- K3: B2 + B3 chained MFMA (128 thr, grid 32 x 128, 2 bc/block) ----------------
// Reads W[bc][m1][k3][k2]: 288 contiguous float4 per (bc,m1).
// Barriers/iter: stage -> b1 -> GEMM1+relayout(Zb) -> b2 -> GEMM2+epilogue.
// Race audit: stage(g) writes Bt; readers GEMM1(g-1) all pre-b2(g-1). relayout(g)
// writes Zb; readers GEMM2(g-1) all pre-b1(g). GEMM2(g) reads Zb written pre-b2(g).
__global__ __launch_bounds__(128) void k3_mfma(const float2* __restrict__ W,
                                               float* __restrict__ out) {
  const int m1   = blockIdx.x;   // 0..31
  const int byy  = blockIdx.y;   // 0..127 -> bc = byy*2+g
  const int tid  = threadIdx.x;
  const int lane = tid & 63;
  const int w    = tid >> 6;     // 0..1

  __shared__ __align__(16) float Bt[32 * 68];   // [col=k3][kap: k2|24+k2|pad]
  __shared__ __align__(16) float Zb[32 * 68];   // [m2][kap: k3|24+k3|pad]

  half8 mbh[4][2], mbl[4][2];
#pragma unroll
  for (int mt = 0; mt < 4; ++mt)
#pragma unroll
    for (int ks = 0; ks < 2; ++ks) {
      mbh[mt][ks] = *(const half8*)&MB2frag[0][mt][ks][lane][0];
      mbl[mt][ks] = *(const half8*)&MB2frag[1][mt][ks][lane][0];
    }
  half8 tb3h[2], tb3l[2];
#pragma unroll
  for (int ks = 0; ks < 2; ++ks) {
    tb3h[ks] = *(const half8*)&TB3frag[0][w][ks][lane][0];
    tb3l[ks] = *(const half8*)&TB3frag[1][w][ks][lane][0];
  }

  // zero pad regions ONCE (data writes never touch them)
  for (int i = tid; i < 8 * 68; i += 128)  Bt[(24 + i / 68) * 68 + (i % 68)] = 0.f;
  for (int i = tid; i < 24 * 20; i += 128) Bt[(i / 20) * 68 + 48 + (i % 20)] = 0.f;
  for (int i = tid; i < 32 * 20; i += 128) Zb[(i / 20) * 68 + 48 + (i % 20)] = 0.f;

  const int kbase = (lane >> 4) * 8;
  const int c16   = lane & 15;
  const int cc    = w * 16 + c16;
  const int rbase = (lane >> 4) * 4;

  // prologue prefetch (g=0): 288 contiguous float4 (jj=2 only tid<32)
  float4 vr0, vr1, vr2;
  {
    const float4* g4 = (const float4*)(W + (size_t)(byy * 2) * 18432 + (size_t)m1 * 576);
    vr0 = g4[tid];
    vr1 = g4[tid + 128];
    if (tid < 32) vr2 = g4[tid + 256];
  }

  for (int g = 0; g < 2; ++g) {
    const int bc = byy * 2 + g;

    // stage Bt from prefetched regs
    {
      const float4 fr[3] = {vr0, vr1, vr2};
#pragma unroll
      for (int jj = 0; jj < 3; ++jj) {
        const int i4 = tid + 128 * jj;
        if (jj < 2 || tid < 32) {
          const int k3 = i4 / 12, c4 = i4 % 12;
          const float4 f = fr[jj];
          Bt[k3 * 68 + 2 * c4]          = f.x;
          Bt[k3 * 68 + 24 + 2 * c4]     = f.y;
          Bt[k3 * 68 + 2 * c4 + 1]      = f.z;
          Bt[k3 * 68 + 24 + 2 * c4 + 1] = f.w;
        }
      }
    }
    // prefetch next bc
    if (g < 1) {
      const float4* g4 = (const float4*)(W + (size_t)(bc + 1) * 18432 + (size_t)m1 * 576);
      vr0 = g4[tid];
      vr1 = g4[tid + 128];
      if (tid < 32) vr2 = g4[tid + 256];
    }
    __syncthreads();   // b1: Bt staged (and prev GEMM2's Zb reads done)

    // GEMM1: [Zr;Zi](64 x k3) = MB2 * [Wr;Wi]
    f32x4 z0 = {}, z1 = {}, z2 = {}, z3 = {};
#pragma unroll
    for (int ks = 0; ks < 2; ++ks) {
      const float4 q0 = *(const float4*)&Bt[cc * 68 + ks * 32 + kbase];
      const float4 q1 = *(const float4*)&Bt[cc * 68 + ks * 32 + kbase + 4];
      const float qf[8] = {q0.x, q0.y, q0.z, q0.w, q1.x, q1.y, q1.z, q1.w};
      half8 bh, bl;
      split8(qf, bh, bl);
#pragma unroll
      for (int mt = 0; mt < 4; ++mt) {
        f32x4& acc = (mt == 0) ? z0 : (mt == 1) ? z1 : (mt == 2) ? z2 : z3;
        acc = __builtin_amdgcn_mfma_f32_16x16x32_f16(mbh[mt][ks], bh, acc, 0, 0, 0);
        acc = __builtin_amdgcn_mfma_f32_16x16x32_f16(mbh[mt][ks], bl, acc, 0, 0, 0);
        acc = __builtin_amdgcn_mfma_f32_16x16x32_f16(mbl[mt][ks], bh, acc, 0, 0, 0);
      }
    }
    // relayout: Zb[m2][k3] = Zr, Zb[m2][24+k3] = Zi
    if (cc < 24) {
#pragma unroll
      for (int mt = 0; mt < 4; ++mt) {
        const f32x4 acc = (mt == 0) ? z0 : (mt == 1) ? z1 : (mt == 2) ? z2 : z3;
        const int row0 = mt * 16 + rbase;
#pragma unroll
        for (int r = 0; r < 4; ++r) {
          const int row = row0 + r;
          if (row < 32) Zb[row * 68 + cc]              = acc[r];
          else          Zb[(row - 32) * 68 + 24 + cc]  = acc[r];
        }
      }
    }
    __syncthreads();   // b2: Zb visible (and all Bt reads done)

    // GEMM2: out(32x32) = Z(32 x 48p64) * TB3
    f32x4 o0 = {}, o1 = {};
#pragma unroll
    for (int ks = 0; ks < 2; ++ks) {
#pragma unroll
      for (int mt = 0; mt < 2; ++mt) {
        const float4 q0 = *(const float4*)&Zb[(mt * 16 + c16) * 68 + ks * 32 + kbase];
        const float4 q1 = *(const float4*)&Zb[(mt * 16 + c16) * 68 + ks * 32 + kbase + 4];
        const float qf[8] = {q0.x, q0.y, q0.z, q0.w, q1.x, q1.y, q1.z, q1.w};
        half8 ah, al;
        split8(qf, ah, al);
        f32x4& acc = (mt == 0) ? o0 : o1;
        acc = __builtin_amdgcn_mfma_f32_16x16x32_f16(ah, tb3h[ks], acc, 0, 0, 0);
        acc = __builtin_amdgcn_mfma_f32_16x16x32_f16(ah, tb3l[ks], acc, 0, 0, 0);
        acc = __builtin_amdgcn_mfma_f32_16x16x32_f16(al, tb3h[ks], acc, 0, 0, 0);
      }
    }
    float* op = out + (size_t)(bc * 32 + m1) * 1024;
#pragma unroll
    for (int mt = 0; mt < 2; ++mt) {
      const f32x4 acc = (mt == 0) ? o0 : o1;
#pragma unroll
      for (int r = 0; r < 4; ++r) {
        const int m2 = mt * 16 + rbase + r;
        op[m2 * 32 + cc] = acc[r] * NORM_F;
      }
    }
  }

  // set lazy-init flag: runs strictly after k_init_tw in stream order, so the
  // NEXT kernel_launch's k_init_tw can safely early-exit (tables are pure consts).
  if (tid == 0 && blockIdx.x == 0 && blockIdx.y == 0) g_twdone = 1;
}

extern "C" void kernel_launch(void* const* d_in, const int* in_sizes, int n_in,
                              void* d_out, int out_size, void* d_ws, size_t ws_size,
                              hipStream_t stream) {
  const float* x = (const float*)d_in[0];
  float* out = (float*)d_out;
  float2* V = (float2*)d_ws;                                   // 56,623,104 B
  float2* W = (float2*)((char*)d_ws + 56623104);               // 37,748,736 B

  k_init_tw  <<<dim3(60), dim3(256), 0, stream>>>();
  k_a12_mfma <<<dim3(12, 256), dim3(384), 0, stream>>>(x, V);
  k2_mfma    <<<dim3(24, 64), dim3(192), 0, stream>>>(V, W);
  k3_mfma    <<<dim3(32, 128), dim3(128), 0, stream>>>(W, out);
}

// Round 7
// 80.107 us; speedup vs baseline: 2.7639x; 1.2483x over previous
//
#include <hip/hip_runtime.h>
#include <math.h>

// SpectralPooling: out = Re(ifft3_32(pad32(crop24(Re(fft3_48(x))))))  per (b,c) volume.
// bc = 256 volumes of 48^3 fp32 -> 256 x 32^3 fp32.
//
// r16: K1 -> WAVE-SLAB, ZERO BARRIERS. Evidence: K1 is ~74us of r15's 100us with all
// pipes idle (Mfma 11%, VALU 16%, HBM 19%) and two rounds (r13/r15) show barrier
// coupling makes it worse -> remove barriers entirely. One 64-thread wave owns one
// slab (bc,n1): X fragments loaded DIRECTLY from global (each B-frag = 8 contiguous
// f32 = 2 aligned float4; no X staging, no b1), GEMM1 -> U dump to wave-private LDS
// (same-wave DS ordering, no b2), GEMM2 holds 9 accs in VGPRs -> D2 dump OVERLAYS
// the dead U arena (DS pipe in-order per wave; aliasing visible via shared base),
// epilogue reads D2 (no b3). LDS/block 13824 B. Per-accumulator MFMA order identical
// to r11 -> bitwise-identical results (absmax must stay 0.00390625).
// K2/K3/init verbatim r11 (best verified split, 81.4us).
//  K1 (per (bc,n1) wave): D1 = T1*X ; D2 = D1*T2t ; recombine -> V
//  K2 (per k3, 2x bc-pair): [Wr;Wi](64x48) = M_comb(64x96) * [Vr;Vi](96x48) -> W
//  K3 (per m1, 2x bc): [Zr;Zi] = MB2*[Wr;Wi] ; out = Z*TB3
// Split-f16 everywhere: P = Ahi*Bhi + Ahi*Blo + Alo*Bhi (~22 mantissa bits).
//
// d_ws: float2 V[256][24][48][24] (56,623,104 B) then
//       float2 W[256][32][24][24] (37,748,736 B) at byte offset 56,623,104.

#define TWO_PI_48 0.13089969389957470f
#define TWO_PI_32 0.19634954084936207f
#define NORM_F    1.6611664e-05f         // 1/(48^1.5 * 32^1.5)

typedef _Float16 half8  __attribute__((ext_vector_type(8)));
typedef _Float16 half4v __attribute__((ext_vector_type(4)));
typedef float    f32x4  __attribute__((ext_vector_type(4)));

// Frag-layout tables: [hi/lo][tile][kstep][lane][j]
// A-frag element = A[tile*16 + (l&15)][ks*32 + (l>>4)*8 + j]
// B-frag element = B[ks*32 + (l>>4)*8 + j][tile*16 + (l&15)]
__device__ _Float16 T1frag[2][3][2][64][8];
__device__ _Float16 T2frag[2][3][2][64][8];
__device__ __align__(16) _Float16 TK2frag[2][4][3][64][8];  // M_comb 64x96
__device__ __align__(16) _Float16 MB2frag[2][4][2][64][8];  // 64x48 (pad 64)
__device__ __align__(16) _Float16 TB3frag[2][2][2][64][8];  // 48(pad64)x32

__device__ int g_twdone = 0;   // lazy-init flag (module-lifetime, set post-init)

__global__ void k_init_tw() {
  if (g_twdone) return;                             // tables already built (pure consts)
  const int idx = blockIdx.x * 256 + threadIdx.x;   // 0..15359
  if (idx < 3072) {                                 // K1 tables (verified r5)
    const int j  = idx & 7;
    const int l  = (idx >> 3) & 63;
    const int ks = (idx >> 9) & 1;
    const int t  = idx >> 10;
    const int k  = ks * 32 + (l >> 4) * 8 + j;
    {
      const int m = t * 16 + (l & 15);
      float v = 0.f;
      if (k < 48) {
        const float a = (float)(((m % 24) * k) % 48) * TWO_PI_48;
        v = (m < 24) ? cosf(a) : -sinf(a);
      }
      const _Float16 h = (_Float16)v;
      T1frag[0][t][ks][l][j] = h;
      T1frag[1][t][ks][l][j] = (_Float16)(v - (float)h);
    }
    {
      const int c = t * 16 + (l & 15);
      float v = 0.f;
      if (k < 48) {
        const float a = (float)(((c % 24) * k) % 48) * TWO_PI_48;
        v = (c < 24) ? cosf(a) : sinf(a);
      }
      const _Float16 h = (_Float16)v;
      T2frag[0][t][ks][l][j] = h;
      T2frag[1][t][ks][l][j] = (_Float16)(v - (float)h);
    }
  } else if (idx < 3072 + 6144) {                   // K2: M_comb (A3+B1 fused)
    const int local = idx - 3072;
    const int j = local & 7, l = (local >> 3) & 63;
    const int rest = local >> 9;                    // 0..11
    const int ks = rest % 3, mt = rest / 3;
    const int m   = mt * 16 + (l & 15);             // 0..63
    const int kap = ks * 32 + (l >> 4) * 8 + j;     // 0..95
    const int n1  = kap % 48;
    const bool isVi = kap >= 48;
    const int m1  = m & 31;
    const bool isWi = m >= 32;
    float acc = 0.f;
    for (int k1 = 0; k1 < 24; ++k1) {
      float s32v, c32v, s48v, c48v;
      sincosf((float)((k1 * m1) % 32) * TWO_PI_32, &s32v, &c32v);
      sincosf((float)((k1 * n1) % 48) * TWO_PI_48, &s48v, &c48v);
      acc = fmaf(isWi ? s32v : c32v, isVi ? s48v : c48v, acc);
    }
    const _Float16 h = (_Float16)acc;
    TK2frag[0][mt][ks][l][j] = h;
    TK2frag[1][mt][ks][l][j] = (_Float16)(acc - (float)h);
  } else if (idx < 3072 + 6144 + 4096) {            // K3: MB2 (B2 A-matrix)
    const int local = idx - (3072 + 6144);
    const int j = local & 7, l = (local >> 3) & 63;
    const int rest = local >> 9;                    // 0..7
    const int ks = rest & 1, mt = rest >> 1;
    const int m   = mt * 16 + (l & 15);             // 0..63
    const int kap = ks * 32 + (l >> 4) * 8 + j;     // 0..63
    float v = 0.f;
    if (kap < 48) {
      const int k2 = kap % 24;
      const int m2 = m & 31;
      float s, c;
      sincosf((float)((k2 * m2) % 32) * TWO_PI_32, &s, &c);
      if (m < 32) v = (kap < 24) ? c : -s;   // Zr = sum Wr*c - Wi*s
      else        v = (kap < 24) ? s :  c;   // Zi = sum Wr*s + Wi*c
    }
    const _Float16 h = (_Float16)v;
    MB2frag[0][mt][ks][l][j] = h;
    MB2frag[1][mt][ks][l][j] = (_Float16)(v - (float)h);
  } else if (idx < 15360) {                         // K3: TB3 (B3 B-matrix)
    const int local = idx - (3072 + 6144 + 4096);
    const int j = local & 7, l = (local >> 3) & 63;
    const int rest = local >> 9;                    // 0..3
    const int ks = rest & 1, nt = rest >> 1;
    const int m3  = nt * 16 + (l & 15);             // col 0..31
    const int kap = ks * 32 + (l >> 4) * 8 + j;     // 0..63
    float v = 0.f;
    if (kap < 48) {
      const int k3 = kap % 24;
      float s, c;
      sincosf((float)((k3 * m3) % 32) * TWO_PI_32, &s, &c);
      v = (kap < 24) ? c : -s;               // out = sum Zr*c - Zi*s
    }
    const _Float16 h = (_Float16)v;
    TB3frag[0][nt][ks][l][j] = h;
    TB3frag[1][nt][ks][l][j] = (_Float16)(v - (float)h);
  }
}

__device__ inline void split8(const float* qf, half8& h, half8& lo) {
#pragma unroll
  for (int j = 0; j < 8; ++j) {
    const _Float16 hh = (_Float16)qf[j];
    h[j]  = hh;
    lo[j] = (_Float16)(qf[j] - (float)hh);
  }
}

// ---------------- K1: wave-slab, 64 thr, grid 48 x 256, ZERO barriers ----------------
// LDS arena (13824 B): Uh[48][72] f16 (6912) + Ul[48][72] f16 (6912); D2 f32 [48][68]
// (13056) OVERLAYS the arena after GEMM2 (U dead; DS pipe in-order per wave; compiler
// sees aliasing through the shared arena base).
// X fragments load directly from global: B-elem = X_mem[c][k], c = nt*16+(lane&15),
// k = ks*32+(lane>>4)*8+j -> 8 contiguous f32 at xs + c*48 + k (32B-aligned since
// k%8==0 and rows are 192B). k>=48 (ks=1, lane>=32) -> zero fragment (= r11's X pad).
__global__ __launch_bounds__(64) void k1_waveslab(const float* __restrict__ x,
                                                  float2* __restrict__ V) {
  const int n1   = blockIdx.x;   // 0..47
  const int bc   = blockIdx.y;   // 0..255
  const int lane = threadIdx.x;  // 0..63

  __shared__ __align__(16) unsigned char arena[13824];
  _Float16* Uh = (_Float16*)arena;
  _Float16* Ul = (_Float16*)(arena + 6912);
  float*    D2 = (float*)arena;               // overlay, used after GEMM2

  const int c16  = lane & 15;
  const int kgrp = lane >> 4;    // 0..3
  const int kb   = kgrp * 8;

  // twiddle fragments (all tiles; this wave does the whole slab)
  half8 t1h[3][2], t1l[3][2], t2h[3][2], t2l[3][2];
#pragma unroll
  for (int mt = 0; mt < 3; ++mt)
#pragma unroll
    for (int ks = 0; ks < 2; ++ks) {
      t1h[mt][ks] = *(const half8*)&T1frag[0][mt][ks][lane][0];
      t1l[mt][ks] = *(const half8*)&T1frag[1][mt][ks][lane][0];
      t2h[mt][ks] = *(const half8*)&T2frag[0][mt][ks][lane][0];
      t2l[mt][ks] = *(const half8*)&T2frag[1][mt][ks][lane][0];
    }

  // zero U pad cols 48..63 (GEMM2 A-frags read k up to 63; data dump touches 0..47
  // only -> disjoint, safe to do now; same-wave lgkmcnt orders vs GEMM2 reads)
#pragma unroll
  for (int p = 0; p < 3; ++p) {
    const int i = lane + 64 * p;            // 0..191
    const int which = i / 48, r = i % 48;
    _Float16* base = (which & 2) ? Ul : Uh;
    *(half8*)&base[r * 72 + 48 + (which & 1) * 8] = (half8){};
  }

  const float* xs = x + (size_t)(bc * 48 + n1) * 2304;

  // ---- GEMM1: D1 = T1 * X, per col-tile nt; U dump after each nt ----
  // prefetch nt=0 fragments
  float4 fa0, fb0, fa1, fb1;                  // ks=0 / ks=1 fragment halves
  {
    const float4* p0 = (const float4*)(xs + c16 * 48 + kb);          // ks=0: k=kb<32
    fa0 = p0[0]; fb0 = p0[1];
    const int k1i = 32 + kb;
    if (k1i < 48) {
      const float4* p1 = (const float4*)(xs + c16 * 48 + k1i);
      fa1 = p1[0]; fb1 = p1[1];
    } else { fa1 = make_float4(0.f,0.f,0.f,0.f); fb1 = fa1; }
  }

#pragma unroll
  for (int nt = 0; nt < 3; ++nt) {
    // prefetch next nt
    float4 na0, nb0, na1, nb1;
    if (nt < 2) {
      const int c = (nt + 1) * 16 + c16;
      const float4* p0 = (const float4*)(xs + c * 48 + kb);
      na0 = p0[0]; nb0 = p0[1];
      const int k1i = 32 + kb;
      if (k1i < 48) {
        const float4* p1 = (const float4*)(xs + c * 48 + k1i);
        na1 = p1[0]; nb1 = p1[1];
      } else { na1 = make_float4(0.f,0.f,0.f,0.f); nb1 = na1; }
    }

    f32x4 acc0 = {}, acc1 = {}, acc2 = {};
#pragma unroll
    for (int ks = 0; ks < 2; ++ks) {
      const float4 qa = ks ? fa1 : fa0;
      const float4 qb = ks ? fb1 : fb0;
      const float qf[8] = {qa.x, qa.y, qa.z, qa.w, qb.x, qb.y, qb.z, qb.w};
      half8 bh, bl;
      split8(qf, bh, bl);
#pragma unroll
      for (int mt = 0; mt < 3; ++mt) {
        f32x4& acc = (mt == 0) ? acc0 : (mt == 1) ? acc1 : acc2;
        acc = __builtin_amdgcn_mfma_f32_16x16x32_f16(t1h[mt][ks], bh, acc, 0, 0, 0);
        acc = __builtin_amdgcn_mfma_f32_16x16x32_f16(t1h[mt][ks], bl, acc, 0, 0, 0);
        acc = __builtin_amdgcn_mfma_f32_16x16x32_f16(t1l[mt][ks], bh, acc, 0, 0, 0);
      }
    }

    // U dump for this nt (cols nt*16+c16; C-frag row = (lane>>4)*4 + r within tile mt)
    {
      const int cc = nt * 16 + c16;
#pragma unroll
      for (int mt = 0; mt < 3; ++mt) {
        const int r0 = mt * 16 + kgrp * 4;
        const f32x4 acc = (mt == 0) ? acc0 : (mt == 1) ? acc1 : acc2;
#pragma unroll
        for (int r = 0; r < 4; ++r) {
          const float v = acc[r];
          const _Float16 h = (_Float16)v;
          Uh[(r0 + r) * 72 + cc] = h;
          Ul[(r0 + r) * 72 + cc] = (_Float16)(v - (float)h);
        }
      }
    }

    fa0 = na0; fb0 = nb0; fa1 = na1; fb1 = nb1;
  }

  // ---- GEMM2: D2 = U * T2t, all 9 output tiles held in VGPRs ----
  // per-acc order identical to r11: ks0 {ah*t2h, ah*t2l, al*t2h} then ks1.
  f32x4 a2[3][3] = {};   // [mt][nt2], fully unrolled indices (static)
#pragma unroll
  for (int ks = 0; ks < 2; ++ks) {
#pragma unroll
    for (int mt = 0; mt < 3; ++mt) {
      const half8 ah = *(const half8*)&Uh[(mt * 16 + c16) * 72 + ks * 32 + kb];
      const half8 al = *(const half8*)&Ul[(mt * 16 + c16) * 72 + ks * 32 + kb];
#pragma unroll
      for (int nt2 = 0; nt2 < 3; ++nt2) {
        a2[mt][nt2] = __builtin_amdgcn_mfma_f32_16x16x32_f16(ah, t2h[nt2][ks], a2[mt][nt2], 0, 0, 0);
        a2[mt][nt2] = __builtin_amdgcn_mfma_f32_16x16x32_f16(ah, t2l[nt2][ks], a2[mt][nt2], 0, 0, 0);
        a2[mt][nt2] = __builtin_amdgcn_mfma_f32_16x16x32_f16(al, t2h[nt2][ks], a2[mt][nt2], 0, 0, 0);
      }
    }
  }

  // D2 dump overlaying the arena (all U reads issued above; DS pipe is in-order
  // per wave, and the compiler sees the aliasing through the arena base).
#pragma unroll
  for (int mt = 0; mt < 3; ++mt)
#pragma unroll
    for (int nt2 = 0; nt2 < 3; ++nt2) {
      const int r0 = mt * 16 + kgrp * 4;
      const int cc = nt2 * 16 + c16;
#pragma unroll
      for (int r = 0; r < 4; ++r)
        D2[(r0 + r) * 68 + cc] = a2[mt][nt2][r];
    }

  // epilogue: recombine -> V[bc][k3][n1][k2] (576 float2; 9 per lane)
#pragma unroll
  for (int q = 0; q < 9; ++q) {
    const int idx = lane + 64 * q;          // 0..575
    const int k3 = idx / 24, k2 = idx % 24;
    const float grr = D2[k3 * 68 + k2];
    const float gis = D2[(k3 + 24) * 68 + k2 + 24];
    const float gir = D2[(k3 + 24) * 68 + k2];
    const float grs = D2[k3 * 68 + k2 + 24];
    V[(size_t)bc * 27648 + (size_t)k3 * 1152 + n1 * 24 + k2] =
        make_float2(grr + gis, gir - grs);
  }
}

// ---------------- K2: A3+B1 fused MFMA GEMM (192 thr, grid 24 x 64, 2 bc-pairs/block) ----------------
// Writes W[bc][m1][k3][k2] (separate buffer, m1-major) so K3 reads are contiguous.
__global__ __launch_bounds__(192) void k2_mfma(const float2* __restrict__ V,
                                               float2* __restrict__ W) {
  const int k3   = blockIdx.x;    // 0..23
  const int byy  = blockIdx.y;    // 0..63 -> bcp = byy*2+g
  const int tid  = threadIdx.x;
  const int lane = tid & 63;
  const int w    = tid >> 6;      // 0..2

  __shared__ __align__(16) float Bb[48 * 100];  // [col=s*24+k2][kap 0..95]

  half8 kth[4][3], ktl[4][3];
#pragma unroll
  for (int mt = 0; mt < 4; ++mt)
#pragma unroll
    for (int ks = 0; ks < 3; ++ks) {
      kth[mt][ks] = *(const half8*)&TK2frag[0][mt][ks][lane][0];
      ktl[mt][ks] = *(const half8*)&TK2frag[1][mt][ks][lane][0];
    }

  const int kbase = (lane >> 4) * 8;
  const int c16   = lane & 15;
  const int cc    = w * 16 + c16;       // 0..47
  const int sE    = cc / 24, k2E = cc % 24;
  const int rbase = (lane >> 4) * 4;

  // prologue prefetch (g=0): 6 float4/thread; s = jj/3, r = tid + 192*(jj%3)
  float4 vr[6];
  {
    const float4* g0 = (const float4*)(V + ((size_t)((byy * 4 + 0) * 24 + k3)) * 1152);
    const float4* g1 = (const float4*)(V + ((size_t)((byy * 4 + 1) * 24 + k3)) * 1152);
#pragma unroll
    for (int jj = 0; jj < 6; ++jj)
      vr[jj] = (jj < 3 ? g0 : g1)[tid + 192 * (jj % 3)];
  }

  for (int g = 0; g < 2; ++g) {
    const int bcp = byy * 2 + g;

    if (g) __syncthreads();   // prev iteration's Bb reads done

    // stage from prefetched regs
#pragma unroll
    for (int jj = 0; jj < 6; ++jj) {
      const int s = jj / 3;
      const int r = tid + 192 * (jj % 3);     // 0..575 within slab
      const int n1 = r / 12, c4 = r % 12;
      const float4 f = vr[jj];
      float* bp = &Bb[(s * 24 + c4 * 2) * 100 + n1];
      bp[0]   = f.x;  bp[48]  = f.y;
      bp[100] = f.z;  bp[148] = f.w;
    }
    // prefetch next bc-pair
    if (g < 1) {
      const float4* g0 = (const float4*)(V + ((size_t)((bcp * 2 + 2) * 24 + k3)) * 1152);
      const float4* g1 = (const float4*)(V + ((size_t)((bcp * 2 + 3) * 24 + k3)) * 1152);
#pragma unroll
      for (int jj = 0; jj < 6; ++jj)
        vr[jj] = (jj < 3 ? g0 : g1)[tid + 192 * (jj % 3)];
    }
    __syncthreads();

    f32x4 a0 = {}, a1 = {}, a2 = {}, a3 = {};
#pragma unroll
    for (int ks = 0; ks < 3; ++ks) {
      const float4 q0 = *(const float4*)&Bb[cc * 100 + ks * 32 + kbase];
      const float4 q1 = *(const float4*)&Bb[cc * 100 + ks * 32 + kbase + 4];
      const float qf[8] = {q0.x, q0.y, q0.z, q0.w, q1.x, q1.y, q1.z, q1.w};
      half8 bh, bl;
      split8(qf, bh, bl);
#pragma unroll
      for (int mt = 0; mt < 4; ++mt) {
        f32x4& acc = (mt == 0) ? a0 : (mt == 1) ? a1 : (mt == 2) ? a2 : a3;
        acc = __builtin_amdgcn_mfma_f32_16x16x32_f16(kth[mt][ks], bh, acc, 0, 0, 0);
        acc = __builtin_amdgcn_mfma_f32_16x16x32_f16(kth[mt][ks], bl, acc, 0, 0, 0);
        acc = __builtin_amdgcn_mfma_f32_16x16x32_f16(ktl[mt][ks], bh, acc, 0, 0, 0);
      }
    }

    // epilogue: rows 0..31 = Wr, rows 32..63 = Wi -> W[bc][m1][k3][k2]
    const int bc = bcp * 2 + sE;
    float2* wp = W + (size_t)bc * 18432 + (size_t)k3 * 24 + k2E;
#pragma unroll
    for (int mt = 0; mt < 2; ++mt) {
      const f32x4 wr = (mt == 0) ? a0 : a1;
      const f32x4 wi = (mt == 0) ? a2 : a3;
#pragma unroll
      for (int r = 0; r < 4; ++r) {
        const int m1 = mt * 16 + rbase + r;
        wp[(size_t)m1 * 576] = make_float2(wr[r], wi[r]);
      }
    }
  }
}

// ---------------- K3: B2 + B3 chained MFMA (128 thr, grid 32 x 128, 2 bc/block) ----------------
// Reads W[bc][m1][k3][k2]: 288 contiguous float4 per (bc,m1).
// Barriers/iter: stage -> b1 -> GEMM1+relayout(Zb) -> b2 -> GEMM2+epilogue.
// Race audit: stage(g) writes Bt; readers GEMM1(g-1) all pre-b2(g-1). relayout(g)
// writes Zb; readers GEMM2(g-1) all pre-b1(g). GEMM2(g) reads Zb written pre-b2(g).
__global__ __launch_bounds__(128) void k3_mfma(const float2* __restrict__ W,
                                               float* __restrict__ out) {
  const int m1   = blockIdx.x;   // 0..31
  const int byy  = blockIdx.y;   // 0..127 -> bc = byy*2+g
  const int tid  = threadIdx.x;
  const int lane = tid & 63;
  const int w    = tid >> 6;     // 0..1

  __shared__ __align__(16) float Bt[32 * 68];   // [col=k3][kap: k2|24+k2|pad]
  __shared__ __align__(16) float Zb[32 * 68];   // [m2][kap: k3|24+k3|pad]

  half8 mbh[4][2], mbl[4][2];
#pragma unroll
  for (int mt = 0; mt < 4; ++mt)
#pragma unroll
    for (int ks = 0; ks < 2; ++ks) {
      mbh[mt][ks] = *(const half8*)&MB2frag[0][mt][ks][lane][0];
      mbl[mt][ks] = *(const half8*)&MB2frag[1][mt][ks][lane][0];
    }
  half8 tb3h[2], tb3l[2];
#pragma unroll
  for (int ks = 0; ks < 2; ++ks) {
    tb3h[ks] = *(const half8*)&TB3frag[0][w][ks][lane][0];
    tb3l[ks] = *(const half8*)&TB3frag[1][w][ks][lane][0];
  }

  // zero pad regions ONCE (data writes never touch them)
  for (int i = tid; i < 8 * 68; i += 128)  Bt[(24 + i / 68) * 68 + (i % 68)] = 0.f;
  for (int i = tid; i < 24 * 20; i += 128) Bt[(i / 20) * 68 + 48 + (i % 20)] = 0.f;
  for (int i = tid; i < 32 * 20; i += 128) Zb[(i / 20) * 68 + 48 + (i % 20)] = 0.f;

  const int kbase = (lane >> 4) * 8;
  const int c16   = lane & 15;
  const int cc    = w * 16 + c16;
  const int rbase = (lane >> 4) * 4;

  // prologue prefetch (g=0): 288 contiguous float4 (jj=2 only tid<32)
  float4 vr0, vr1, vr2;
  {
    const float4* g4 = (const float4*)(W + (size_t)(byy * 2) * 18432 + (size_t)m1 * 576);
    vr0 = g4[tid];
    vr1 = g4[tid + 128];
    if (tid < 32) vr2 = g4[tid + 256];
  }

  for (int g = 0; g < 2; ++g) {
    const int bc = byy * 2 + g;

    // stage Bt from prefetched regs
    {
      const float4 fr[3] = {vr0, vr1, vr2};
#pragma unroll
      for (int jj = 0; jj < 3; ++jj) {
        const int i4 = tid + 128 * jj;
        if (jj < 2 || tid < 32) {
          const int k3 = i4 / 12, c4 = i4 % 12;
          const float4 f = fr[jj];
          Bt[k3 * 68 + 2 * c4]          = f.x;
          Bt[k3 * 68 + 24 + 2 * c4]     = f.y;
          Bt[k3 * 68 + 2 * c4 + 1]      = f.z;
          Bt[k3 * 68 + 24 + 2 * c4 + 1] = f.w;
        }
      }
    }
    // prefetch next bc
    if (g < 1) {
      const float4* g4 = (const float4*)(W + (size_t)(bc + 1) * 18432 + (size_t)m1 * 576);
      vr0 = g4[tid];
      vr1 = g4[tid + 128];
      if (tid < 32) vr2 = g4[tid + 256];
    }
    __syncthreads();   // b1: Bt staged (and prev GEMM2's Zb reads done)

    // GEMM1: [Zr;Zi](64 x k3) = MB2 * [Wr;Wi]
    f32x4 z0 = {}, z1 = {}, z2 = {}, z3 = {};
#pragma unroll
    for (int ks = 0; ks < 2; ++ks) {
      const float4 q0 = *(const float4*)&Bt[cc * 68 + ks * 32 + kbase];
      const float4 q1 = *(const float4*)&Bt[cc * 68 + ks * 32 + kbase + 4];
      const float qf[8] = {q0.x, q0.y, q0.z, q0.w, q1.x, q1.y, q1.z, q1.w};
      half8 bh, bl;
      split8(qf, bh, bl);
#pragma unroll
      for (int mt = 0; mt < 4; ++mt) {
        f32x4& acc = (mt == 0) ? z0 : (mt == 1) ? z1 : (mt == 2) ? z2 : z3;
        acc = __builtin_amdgcn_mfma_f32_16x16x32_f16(mbh[mt][ks], bh, acc, 0, 0, 0);
        acc = __builtin_amdgcn_mfma_f32_16x16x32_f16(mbh[mt][ks], bl, acc, 0, 0, 0);
        acc = __builtin_amdgcn_mfma_f32_16x16x32_f16(mbl[mt][ks], bh, acc, 0, 0, 0);
      }
    }
    // relayout: Zb[m2][k3] = Zr, Zb[m2][24+k3] = Zi
    if (cc < 24) {
#pragma unroll
      for (int mt = 0; mt < 4; ++mt) {
        const f32x4 acc = (mt == 0) ? z0 : (mt == 1) ? z1 : (mt == 2) ? z2 : z3;
        const int row0 = mt * 16 + rbase;
#pragma unroll
        for (int r = 0; r < 4; ++r) {
          const int row = row0 + r;
          if (row < 32) Zb[row * 68 + cc]              = acc[r];
          else          Zb[(row - 32) * 68 + 24 + cc]  = acc[r];
        }
      }
    }
    __syncthreads();   // b2: Zb visible (and all Bt reads done)

    // GEMM2: out(32x32) = Z(32 x 48p64) * TB3
    f32x4 o0 = {}, o1 = {};
#pragma unroll
    for (int ks = 0; ks < 2; ++ks) {
#pragma unroll
      for (int mt = 0; mt < 2; ++mt) {
        const float4 q0 = *(const float4*)&Zb[(mt * 16 + c16) * 68 + ks * 32 + kbase];
        const float4 q1 = *(const float4*)&Zb[(mt * 16 + c16) * 68 + ks * 32 + kbase + 4];
        const float qf[8] = {q0.x, q0.y, q0.z, q0.w, q1.x, q1.y, q1.z, q1.w};
        half8 ah, al;
        split8(qf, ah, al);
        f32x4& acc = (mt == 0) ? o0 : o1;
        acc = __builtin_amdgcn_mfma_f32_16x16x32_f16(ah, tb3h[ks], acc, 0, 0, 0);
        acc = __builtin_amdgcn_mfma_f32_16x16x32_f16(ah, tb3l[ks], acc, 0, 0, 0);
        acc = __builtin_amdgcn_mfma_f32_16x16x32_f16(al, tb3h[ks], acc, 0, 0, 0);
      }
    }
    float* op = out + (size_t)(bc * 32 + m1) * 1024;
#pragma unroll
    for (int mt = 0; mt < 2; ++mt) {
      const f32x4 acc = (mt == 0) ? o0 : o1;
#pragma unroll
      for (int r = 0; r < 4; ++r) {
        const int m2 = mt * 16 + rbase + r;
        op[m2 * 32 + cc] = acc[r] * NORM_F;
      }
    }
  }

  // set lazy-init flag: runs strictly after k_init_tw in stream order, so the
  // NEXT kernel_launch's k_init_tw can safely early-exit (tables are pure consts).
  if (tid == 0 && blockIdx.x == 0 && blockIdx.y == 0) g_twdone = 1;
}

extern "C" void kernel_launch(void* const* d_in, const int* in_sizes, int n_in,
                              void* d_out, int out_size, void* d_ws, size_t ws_size,
                              hipStream_t stream) {
  const float* x = (const float*)d_in[0];
  float* out = (float*)d_out;
  float2* V = (float2*)d_ws;                                   // 56,623,104 B
  float2* W = (float2*)((char*)d_ws + 56623104);               // 37,748,736 B

  k_init_tw   <<<dim3(60), dim3(256), 0, stream>>>();
  k1_waveslab <<<dim3(48, 256), dim3(64), 0, stream>>>(x, V);
  k2_mfma     <<<dim3(24, 64), dim3(192), 0, stream>>>(V, W);
  k3_mfma     <<<dim3(32, 128), dim3(128), 0, stream>>>(W, out);
}